// Round 2
// baseline (693.438 us; speedup 1.0000x reference)
//
#include <hip/hip_runtime.h>
#include <hip/hip_bf16.h>

#define T_TOKENS 2048
#define H_DIM    2048
#define I_DIM    1408
#define E_NUM    8

typedef __bf16 bf16;
typedef __attribute__((ext_vector_type(8))) __bf16  bf16x8;
typedef __attribute__((ext_vector_type(4))) float   floatx4;

#define MFMA __builtin_amdgcn_mfma_f32_16x16x32_bf16

// ---------------- ws layout (bytes) ----------------
// gu_pk: [E][11 n-tiles][32 k-tiles][256 r][64 k] bf16, XOR-swizzled granules = 92.3 MB
// dn_pk: [E][ 8 n-tiles][22 k-tiles][256 r][64 k] bf16, swizzled              = 46.1 MB
// tmp overlaps gu_pk (gu_pk dead after gemm1; tmp written by gemm2).
static const size_t OFF_COUNTS = 0;
static const size_t OFF_LISTS  = 256;
static const size_t OFF_WLISTS = OFF_LISTS + (size_t)T_TOKENS * E_NUM * 4;       // 65792
static const size_t OFF_XB     = 131328;                                          // 8 MB
static const size_t OFF_ACT    = OFF_XB + (size_t)T_TOKENS * H_DIM * 2;           // 11.5 MB
static const size_t OFF_GUPK   = OFF_ACT + (size_t)2 * T_TOKENS * I_DIM * 2;
static const size_t OFF_DNPK   = OFF_GUPK + (size_t)E_NUM * 11 * 32 * 32768;
static const size_t OFF_TMP    = OFF_GUPK;   // 33.5 MB, overlapped

// async global->LDS, 16 B per lane; LDS dest is wave-uniform base + lane*16.
__device__ __forceinline__ void gload_lds16(const bf16* g, bf16* l)
{
    __builtin_amdgcn_global_load_lds((const __attribute__((address_space(1))) void*)g,
                                     (__attribute__((address_space(3))) void*)l,
                                     16, 0, 0);
}

// ---------------- pack gate_up: dequant + 256-row tile + gate/up interleave + swizzle ----------------
// B-tile row map: I-col pair p=(icol>>4)&7 (within 128-col tile), r=(p*2+is_up)*16+(icol&15)
__global__ __launch_bounds__(256) void pack_gu_kernel(const int* __restrict__ q,
                                                      const float* __restrict__ sc,
                                                      bf16* __restrict__ out)
{
    const int b = blockIdx.x;
    const int t = threadIdx.x;
    const int e = b / 2816;
    const int grow = b - e * 2816;
    const int4* qp = reinterpret_cast<const int4*>(q + (size_t)b * H_DIM) + t * 2;
    int4 a = qp[0], c = qp[1];
    float s = sc[(size_t)b * 16 + (t >> 4)];
    float m8s = -8.f * s;
    bf16x8 bv;
    bv[0] = (bf16)fmaf((float)a.x, s, m8s);
    bv[1] = (bf16)fmaf((float)a.y, s, m8s);
    bv[2] = (bf16)fmaf((float)a.z, s, m8s);
    bv[3] = (bf16)fmaf((float)a.w, s, m8s);
    bv[4] = (bf16)fmaf((float)c.x, s, m8s);
    bv[5] = (bf16)fmaf((float)c.y, s, m8s);
    bv[6] = (bf16)fmaf((float)c.z, s, m8s);
    bv[7] = (bf16)fmaf((float)c.w, s, m8s);
    const int is_up = grow >= I_DIM;
    const int icol  = grow - (is_up ? I_DIM : 0);
    const int nt    = icol >> 7;
    const int r     = ((((icol >> 4) & 7) * 2 + is_up) << 4) + (icol & 15);
    size_t dst = ((((size_t)e * 11 + nt) * 32 + (t >> 3)) * 256 + r) * 8 + ((t & 7) ^ (r & 7));
    reinterpret_cast<bf16x8*>(out)[dst] = bv;
}

// ---------------- pack down: dequant + 256-row tile + swizzle ----------------
__global__ __launch_bounds__(256) void pack_dn_kernel(const int* __restrict__ q,
                                                      const float* __restrict__ sc,
                                                      bf16* __restrict__ out)
{
    const int b = blockIdx.x;
    const int t = threadIdx.x;
    if (t >= 176) return;
    const int e = b >> 11;
    const int grow = b & 2047;
    const int4* qp = reinterpret_cast<const int4*>(q + (size_t)b * I_DIM) + t * 2;
    int4 a = qp[0], c = qp[1];
    float s = sc[(size_t)b * 11 + (t >> 4)];
    float m8s = -8.f * s;
    bf16x8 bv;
    bv[0] = (bf16)fmaf((float)a.x, s, m8s);
    bv[1] = (bf16)fmaf((float)a.y, s, m8s);
    bv[2] = (bf16)fmaf((float)a.z, s, m8s);
    bv[3] = (bf16)fmaf((float)a.w, s, m8s);
    bv[4] = (bf16)fmaf((float)c.x, s, m8s);
    bv[5] = (bf16)fmaf((float)c.y, s, m8s);
    bv[6] = (bf16)fmaf((float)c.z, s, m8s);
    bv[7] = (bf16)fmaf((float)c.w, s, m8s);
    const int nt = grow >> 8;
    const int r  = grow & 255;
    size_t dst = ((((size_t)e * 8 + nt) * 22 + (t >> 3)) * 256 + r) * 8 + ((t & 7) ^ (r & 7));
    reinterpret_cast<bf16x8*>(out)[dst] = bv;
}

// ---------------- x f32 -> bf16 ----------------
__global__ void xconv_kernel(const float* __restrict__ x, bf16* __restrict__ xb)
{
    int i = blockIdx.x * blockDim.x + threadIdx.x;
    const float4* x4 = reinterpret_cast<const float4*>(x) + (size_t)i * 2;
    float4 v0 = x4[0], v1 = x4[1];
    bf16x8 bv;
    bv[0] = (bf16)v0.x; bv[1] = (bf16)v0.y; bv[2] = (bf16)v0.z; bv[3] = (bf16)v0.w;
    bv[4] = (bf16)v1.x; bv[5] = (bf16)v1.y; bv[6] = (bf16)v1.z; bv[7] = (bf16)v1.w;
    *reinterpret_cast<bf16x8*>(xb + (size_t)i * 8) = bv;
}

// ---------------- routing ----------------
__global__ void router_kernel(const float* __restrict__ logits,
                              int* __restrict__ counts,
                              int* __restrict__ lists,
                              float* __restrict__ wlists)
{
    int t = blockIdx.x * blockDim.x + threadIdx.x;
    if (t >= T_TOKENS) return;
    const float* l = logits + (size_t)t * E_NUM;
    float v0 = -1e30f, v1 = -1e30f;
    int i0 = 0, i1 = 0;
    #pragma unroll
    for (int e = 0; e < E_NUM; ++e) {
        float v = l[e];
        if (v > v0) { v1 = v0; i1 = i0; v0 = v; i0 = e; }
        else if (v > v1) { v1 = v; i1 = e; }
    }
    float w0 = 1.f / (1.f + __expf(v1 - v0));
    float w1 = 1.f - w0;
    int p0 = atomicAdd(&counts[i0], 1);
    lists[i0 * T_TOKENS + p0] = t * 2 + 0;
    wlists[i0 * T_TOKENS + p0] = w0;
    int p1 = atomicAdd(&counts[i1], 1);
    lists[i1 * T_TOKENS + p1] = t * 2 + 1;
    wlists[i1 * T_TOKENS + p1] = w1;
}

// ======================= 256x256 8-phase GEMM kernels =======================
// 8 waves (2M x 4N), per-wave C = 128x64. Double-buffered 64KB-per-tile LDS.
// Per K-tile: 4 phases (A0B0 / A0B1 / A1B1 / A1B0), per-phase s_barrier,
// lgkmcnt(0)+sched_barrier before each 16-MFMA cluster, setprio around MFMA.
// Staging: 8 global_load_lds/thread per K-tile issued in P4 into the buffer
// just vacated; counted s_waitcnt vmcnt(8) at top of each iteration.

#define PHASE_BAR() do { __builtin_amdgcn_sched_barrier(0); \
                         __builtin_amdgcn_s_barrier(); \
                         __builtin_amdgcn_sched_barrier(0); } while (0)
#define LGK0() do { asm volatile("s_waitcnt lgkmcnt(0)" ::: "memory"); \
                    __builtin_amdgcn_sched_barrier(0); } while (0)

#define RD(buf, row, g8) (*reinterpret_cast<const bf16x8*>(&(buf)[(row) * 64 + (g8)]))

// ---------------- GEMM1: xb @ W_gate_up^T, fused SwiGLU ----------------
// grid = E * 11nt * 8mtiles = 704 blocks, m-tile fastest. No XCD pinning:
// ~190 live blocks spread over 256 CUs -> single concurrent round.
__global__ __launch_bounds__(512, 2) void gemm1_kernel(
    const bf16* __restrict__ xb,
    const bf16* __restrict__ wpk,
    const int*  __restrict__ counts,
    const int*  __restrict__ lists,
    bf16*       __restrict__ act)
{
    const int bid = blockIdx.x;
    const int e   = bid / 88;
    const int r_  = bid - e * 88;
    const int nt  = r_ >> 3;
    const int m0  = (r_ & 7) << 8;
    const int cnt = counts[e];
    if (m0 >= cnt) return;

    __shared__ __align__(16) bf16 Al[2][16384];
    __shared__ __align__(16) bf16 Bl[2][16384];
    __shared__ int meta[256];

    const int tid = threadIdx.x;
    if (tid < 256) {
        int m = m0 + tid;
        meta[tid] = lists[e * T_TOKENS + (m < cnt ? m : 0)];
    }
    __syncthreads();

    const int lane = tid & 63;
    const int wm = (tid >> 6) >> 2;
    const int wn = (tid >> 6) & 3;

    // staging addresses: granule slot g = j*512+tid -> row = j*64+(tid>>3),
    // logical cg = (tid&7) ^ (row&7)  (source pre-swizzle; LDS dest linear)
    const int cgp = (((tid & 7) ^ ((tid >> 3) & 7)) << 3);
    size_t aglb[4];
    #pragma unroll
    for (int j = 0; j < 4; ++j)
        aglb[j] = (size_t)(meta[j * 64 + (tid >> 3)] >> 1) * H_DIM + cgp;
    const bf16* bt = wpk + ((size_t)e * 11 + nt) * (32 * 16384) + (size_t)tid * 8;
    const int dst8 = tid * 8;

    floatx4 acc[8][4];
    #pragma unroll
    for (int i = 0; i < 8; ++i)
        #pragma unroll
        for (int j = 0; j < 4; ++j)
            acc[i][j] = (floatx4){0.f, 0.f, 0.f, 0.f};

    // prologue: stage k-tiles 0 and 1
    #pragma unroll
    for (int j = 0; j < 4; ++j) gload_lds16(xb + aglb[j],            &Al[0][dst8 + j * 4096]);
    #pragma unroll
    for (int j = 0; j < 4; ++j) gload_lds16(bt + j * 4096,           &Bl[0][dst8 + j * 4096]);
    #pragma unroll
    for (int j = 0; j < 4; ++j) gload_lds16(xb + aglb[j] + 64,       &Al[1][dst8 + j * 4096]);
    #pragma unroll
    for (int j = 0; j < 4; ++j) gload_lds16(bt + 16384 + j * 4096,   &Bl[1][dst8 + j * 4096]);

    const int l15   = lane & 15;
    const int g80   = (((lane >> 4) ^ (lane & 7)) << 3);
    const int g81   = g80 ^ 32;
    const int abase = wm * 128 + l15;
    const int bbase = wn * 64 + l15;

    for (int kt = 0; kt < 32; ++kt) {
        bf16* Ab = Al[kt & 1];
        bf16* Bb = Bl[kt & 1];
        if (kt == 31) { asm volatile("s_waitcnt vmcnt(0)" ::: "memory"); }
        else          { asm volatile("s_waitcnt vmcnt(8)" ::: "memory"); }
        PHASE_BAR();

        bf16x8 a[4][2], b0[2][2], b1[2][2];
        // ---- P1: read A[qm=0] + B[qn=0]; MFMA -> acc[0..3][0..1]
        #pragma unroll
        for (int mt = 0; mt < 4; ++mt) {
            a[mt][0] = RD(Ab, abase + mt * 16, g80);
            a[mt][1] = RD(Ab, abase + mt * 16, g81);
        }
        #pragma unroll
        for (int nf = 0; nf < 2; ++nf) {
            b0[nf][0] = RD(Bb, bbase + nf * 16, g80);
            b0[nf][1] = RD(Bb, bbase + nf * 16, g81);
        }
        LGK0();
        __builtin_amdgcn_s_setprio(1);
        #pragma unroll
        for (int ks = 0; ks < 2; ++ks)
            #pragma unroll
            for (int mt = 0; mt < 4; ++mt)
                #pragma unroll
                for (int nf = 0; nf < 2; ++nf)
                    acc[mt][nf] = MFMA(a[mt][ks], b0[nf][ks], acc[mt][nf], 0, 0, 0);
        __builtin_amdgcn_s_setprio(0);
        PHASE_BAR();

        // ---- P2: read B[qn=1]; MFMA -> acc[0..3][2..3]
        #pragma unroll
        for (int nf = 0; nf < 2; ++nf) {
            b1[nf][0] = RD(Bb, bbase + 32 + nf * 16, g80);
            b1[nf][1] = RD(Bb, bbase + 32 + nf * 16, g81);
        }
        LGK0();
        __builtin_amdgcn_s_setprio(1);
        #pragma unroll
        for (int ks = 0; ks < 2; ++ks)
            #pragma unroll
            for (int mt = 0; mt < 4; ++mt)
                #pragma unroll
                for (int nf = 0; nf < 2; ++nf)
                    acc[mt][2 + nf] = MFMA(a[mt][ks], b1[nf][ks], acc[mt][2 + nf], 0, 0, 0);
        __builtin_amdgcn_s_setprio(0);
        PHASE_BAR();

        // ---- P3: read A[qm=1]; MFMA -> acc[4..7][2..3]
        #pragma unroll
        for (int mt = 0; mt < 4; ++mt) {
            a[mt][0] = RD(Ab, abase + 64 + mt * 16, g80);
            a[mt][1] = RD(Ab, abase + 64 + mt * 16, g81);
        }
        LGK0();
        __builtin_amdgcn_s_setprio(1);
        #pragma unroll
        for (int ks = 0; ks < 2; ++ks)
            #pragma unroll
            for (int mt = 0; mt < 4; ++mt)
                #pragma unroll
                for (int nf = 0; nf < 2; ++nf)
                    acc[4 + mt][2 + nf] = MFMA(a[mt][ks], b1[nf][ks], acc[4 + mt][2 + nf], 0, 0, 0);
        __builtin_amdgcn_s_setprio(0);
        PHASE_BAR();

        // ---- P4: stage k-tile kt+2 into vacated buffer; MFMA -> acc[4..7][0..1]
        if (kt < 30) {
            #pragma unroll
            for (int j = 0; j < 4; ++j)
                gload_lds16(xb + aglb[j] + (size_t)(kt + 2) * 64, &Ab[dst8 + j * 4096]);
            #pragma unroll
            for (int j = 0; j < 4; ++j)
                gload_lds16(bt + (size_t)(kt + 2) * 16384 + j * 4096, &Bb[dst8 + j * 4096]);
        }
        __builtin_amdgcn_s_setprio(1);
        #pragma unroll
        for (int ks = 0; ks < 2; ++ks)
            #pragma unroll
            for (int mt = 0; mt < 4; ++mt)
                #pragma unroll
                for (int nf = 0; nf < 2; ++nf)
                    acc[4 + mt][nf] = MFMA(a[mt][ks], b0[nf][ks], acc[4 + mt][nf], 0, 0, 0);
        __builtin_amdgcn_s_setprio(0);
        // no barrier: top-of-loop vmcnt + barrier orders the next phase
    }

    // epilogue: SwiGLU (gate = even col-frag, up = odd), scatter to act
    const int rbase = (lane >> 4) * 4;
    const int cn = lane & 15;
    #pragma unroll
    for (int mt = 0; mt < 8; ++mt) {
        #pragma unroll
        for (int q = 0; q < 2; ++q) {
            floatx4 g = acc[mt][2 * q];
            floatx4 u = acc[mt][2 * q + 1];
            int col = nt * 128 + (wn * 2 + q) * 16 + cn;
            #pragma unroll
            for (int r = 0; r < 4; ++r) {
                int lrow = wm * 128 + mt * 16 + rbase + r;
                if (m0 + lrow < cnt) {
                    float gate = g[r], up = u[r];
                    float av = gate / (1.f + __expf(-gate)) * up;
                    act[(size_t)meta[lrow] * I_DIM + col] = (bf16)av;
                }
            }
        }
    }
}

// ---------------- GEMM2: act @ W_down^T, weighted write to tmp ----------------
// grid = E * 8nt * 8mtiles = 512 blocks.
__global__ __launch_bounds__(512, 2) void gemm2_kernel(
    const bf16*  __restrict__ act,
    const bf16*  __restrict__ wpk,
    const int*   __restrict__ counts,
    const int*   __restrict__ lists,
    const float* __restrict__ wlists,
    float*       __restrict__ tmp)
{
    const int bid = blockIdx.x;
    const int e   = bid >> 6;
    const int r_  = bid & 63;
    const int nt  = r_ >> 3;
    const int m0  = (r_ & 7) << 8;
    const int cnt = counts[e];
    if (m0 >= cnt) return;

    __shared__ __align__(16) bf16 Al[2][16384];
    __shared__ __align__(16) bf16 Bl[2][16384];
    __shared__ int   meta[256];
    __shared__ float wmeta[256];

    const int tid = threadIdx.x;
    if (tid < 256) {
        int m = m0 + tid;
        int mm = (m < cnt) ? m : 0;
        meta[tid]  = lists[e * T_TOKENS + mm];
        wmeta[tid] = wlists[e * T_TOKENS + mm];
    }
    __syncthreads();

    const int lane = tid & 63;
    const int wm = (tid >> 6) >> 2;
    const int wn = (tid >> 6) & 3;

    const int cgp = (((tid & 7) ^ ((tid >> 3) & 7)) << 3);
    size_t aglb[4];
    #pragma unroll
    for (int j = 0; j < 4; ++j)
        aglb[j] = (size_t)meta[j * 64 + (tid >> 3)] * I_DIM + cgp;
    const bf16* bt = wpk + ((size_t)e * 8 + nt) * (22 * 16384) + (size_t)tid * 8;
    const int dst8 = tid * 8;

    floatx4 acc[8][4];
    #pragma unroll
    for (int i = 0; i < 8; ++i)
        #pragma unroll
        for (int j = 0; j < 4; ++j)
            acc[i][j] = (floatx4){0.f, 0.f, 0.f, 0.f};

    #pragma unroll
    for (int j = 0; j < 4; ++j) gload_lds16(act + aglb[j],           &Al[0][dst8 + j * 4096]);
    #pragma unroll
    for (int j = 0; j < 4; ++j) gload_lds16(bt + j * 4096,           &Bl[0][dst8 + j * 4096]);
    #pragma unroll
    for (int j = 0; j < 4; ++j) gload_lds16(act + aglb[j] + 64,      &Al[1][dst8 + j * 4096]);
    #pragma unroll
    for (int j = 0; j < 4; ++j) gload_lds16(bt + 16384 + j * 4096,   &Bl[1][dst8 + j * 4096]);

    const int l15   = lane & 15;
    const int g80   = (((lane >> 4) ^ (lane & 7)) << 3);
    const int g81   = g80 ^ 32;
    const int abase = wm * 128 + l15;
    const int bbase = wn * 64 + l15;

    for (int kt = 0; kt < 22; ++kt) {
        bf16* Ab = Al[kt & 1];
        bf16* Bb = Bl[kt & 1];
        if (kt == 21) { asm volatile("s_waitcnt vmcnt(0)" ::: "memory"); }
        else          { asm volatile("s_waitcnt vmcnt(8)" ::: "memory"); }
        PHASE_BAR();

        bf16x8 a[4][2], b0[2][2], b1[2][2];
        #pragma unroll
        for (int mt = 0; mt < 4; ++mt) {
            a[mt][0] = RD(Ab, abase + mt * 16, g80);
            a[mt][1] = RD(Ab, abase + mt * 16, g81);
        }
        #pragma unroll
        for (int nf = 0; nf < 2; ++nf) {
            b0[nf][0] = RD(Bb, bbase + nf * 16, g80);
            b0[nf][1] = RD(Bb, bbase + nf * 16, g81);
        }
        LGK0();
        __builtin_amdgcn_s_setprio(1);
        #pragma unroll
        for (int ks = 0; ks < 2; ++ks)
            #pragma unroll
            for (int mt = 0; mt < 4; ++mt)
                #pragma unroll
                for (int nf = 0; nf < 2; ++nf)
                    acc[mt][nf] = MFMA(a[mt][ks], b0[nf][ks], acc[mt][nf], 0, 0, 0);
        __builtin_amdgcn_s_setprio(0);
        PHASE_BAR();

        #pragma unroll
        for (int nf = 0; nf < 2; ++nf) {
            b1[nf][0] = RD(Bb, bbase + 32 + nf * 16, g80);
            b1[nf][1] = RD(Bb, bbase + 32 + nf * 16, g81);
        }
        LGK0();
        __builtin_amdgcn_s_setprio(1);
        #pragma unroll
        for (int ks = 0; ks < 2; ++ks)
            #pragma unroll
            for (int mt = 0; mt < 4; ++mt)
                #pragma unroll
                for (int nf = 0; nf < 2; ++nf)
                    acc[mt][2 + nf] = MFMA(a[mt][ks], b1[nf][ks], acc[mt][2 + nf], 0, 0, 0);
        __builtin_amdgcn_s_setprio(0);
        PHASE_BAR();

        #pragma unroll
        for (int mt = 0; mt < 4; ++mt) {
            a[mt][0] = RD(Ab, abase + 64 + mt * 16, g80);
            a[mt][1] = RD(Ab, abase + 64 + mt * 16, g81);
        }
        LGK0();
        __builtin_amdgcn_s_setprio(1);
        #pragma unroll
        for (int ks = 0; ks < 2; ++ks)
            #pragma unroll
            for (int mt = 0; mt < 4; ++mt)
                #pragma unroll
                for (int nf = 0; nf < 2; ++nf)
                    acc[4 + mt][2 + nf] = MFMA(a[mt][ks], b1[nf][ks], acc[4 + mt][2 + nf], 0, 0, 0);
        __builtin_amdgcn_s_setprio(0);
        PHASE_BAR();

        if (kt < 20) {
            #pragma unroll
            for (int j = 0; j < 4; ++j)
                gload_lds16(act + aglb[j] + (size_t)(kt + 2) * 64, &Ab[dst8 + j * 4096]);
            #pragma unroll
            for (int j = 0; j < 4; ++j)
                gload_lds16(bt + (size_t)(kt + 2) * 16384 + j * 4096, &Bb[dst8 + j * 4096]);
        }
        __builtin_amdgcn_s_setprio(1);
        #pragma unroll
        for (int ks = 0; ks < 2; ++ks)
            #pragma unroll
            for (int mt = 0; mt < 4; ++mt)
                #pragma unroll
                for (int nf = 0; nf < 2; ++nf)
                    acc[4 + mt][nf] = MFMA(a[mt][ks], b0[nf][ks], acc[4 + mt][nf], 0, 0, 0);
        __builtin_amdgcn_s_setprio(0);
    }

    const int rbase = (lane >> 4) * 4;
    const int cn = lane & 15;
    #pragma unroll
    for (int mt = 0; mt < 8; ++mt) {
        #pragma unroll
        for (int f = 0; f < 4; ++f) {
            floatx4 v = acc[mt][f];
            int col = (nt << 8) + wn * 64 + f * 16 + cn;
            #pragma unroll
            for (int r = 0; r < 4; ++r) {
                int lrow = wm * 128 + mt * 16 + rbase + r;
                if (m0 + lrow < cnt) {
                    tmp[(size_t)meta[lrow] * H_DIM + col] = wmeta[lrow] * v[r];
                }
            }
        }
    }
}

// ---------------- finalize: out[t] = tmp[2t] + tmp[2t+1] ----------------
__global__ void finalize_kernel(const float* __restrict__ tmp, float* __restrict__ out)
{
    int i4 = blockIdx.x * blockDim.x + threadIdx.x;
    int t  = i4 >> 9;
    int h  = (i4 & 511) * 4;
    float4 a = *reinterpret_cast<const float4*>(tmp + ((size_t)2 * t) * H_DIM + h);
    float4 b = *reinterpret_cast<const float4*>(tmp + ((size_t)(2 * t + 1)) * H_DIM + h);
    float4 o;
    o.x = a.x + b.x; o.y = a.y + b.y; o.z = a.z + b.z; o.w = a.w + b.w;
    *reinterpret_cast<float4*>(out + (size_t)t * H_DIM + h) = o;
}

extern "C" void kernel_launch(void* const* d_in, const int* in_sizes, int n_in,
                              void* d_out, int out_size, void* d_ws, size_t ws_size,
                              hipStream_t stream)
{
    const float* router_logits = (const float*)d_in[0];
    const float* x             = (const float*)d_in[1];
    const int*   gu_q          = (const int*)d_in[2];
    const float* gu_s          = (const float*)d_in[3];
    const int*   dn_q          = (const int*)d_in[4];
    const float* dn_s          = (const float*)d_in[5];
    float* out = (float*)d_out;

    char* ws = (char*)d_ws;
    int*   counts = (int*)(ws + OFF_COUNTS);
    int*   lists  = (int*)(ws + OFF_LISTS);
    float* wlists = (float*)(ws + OFF_WLISTS);
    bf16*  xb     = (bf16*)(ws + OFF_XB);
    bf16*  act    = (bf16*)(ws + OFF_ACT);
    bf16*  gu_pk  = (bf16*)(ws + OFF_GUPK);
    bf16*  dn_pk  = (bf16*)(ws + OFF_DNPK);
    float* tmp    = (float*)(ws + OFF_TMP);   // overlaps gu_pk (dead after gemm1)

    hipMemsetAsync(counts, 0, E_NUM * sizeof(int), stream);

    pack_gu_kernel<<<E_NUM * 2816, 256, 0, stream>>>(gu_q, gu_s, gu_pk);
    pack_dn_kernel<<<E_NUM * 2048, 256, 0, stream>>>(dn_q, dn_s, dn_pk);
    xconv_kernel<<<T_TOKENS * H_DIM / 8 / 256, 256, 0, stream>>>(x, xb);
    router_kernel<<<T_TOKENS / 256, 256, 0, stream>>>(router_logits, counts, lists, wlists);

    gemm1_kernel<<<88 * E_NUM, 512, 0, stream>>>(xb, gu_pk, counts, lists, act);
    gemm2_kernel<<<64 * E_NUM, 512, 0, stream>>>(act, dn_pk, counts, lists, wlists, tmp);
    finalize_kernel<<<4096, 256, 0, stream>>>(tmp, out);
}

// Round 3
// 577.050 us; speedup vs baseline: 1.2017x; 1.2017x over previous
//
#include <hip/hip_runtime.h>
#include <hip/hip_bf16.h>

#define T_TOKENS 2048
#define H_DIM    2048
#define I_DIM    1408
#define E_NUM    8

typedef __bf16 bf16;
typedef __attribute__((ext_vector_type(8))) __bf16  bf16x8;
typedef __attribute__((ext_vector_type(4))) float   floatx4;

#define MFMA __builtin_amdgcn_mfma_f32_16x16x32_bf16

// ---------------- ws layout (bytes) ----------------
static const size_t OFF_COUNTS = 0;
static const size_t OFF_LISTS  = 256;
static const size_t OFF_WLISTS = OFF_LISTS + (size_t)T_TOKENS * E_NUM * 4;       // 65792
static const size_t OFF_XB     = 131328;
static const size_t OFF_ACT    = OFF_XB + (size_t)T_TOKENS * H_DIM * 2;           // xb 8 MB
static const size_t OFF_TMP    = OFF_ACT + (size_t)2 * T_TOKENS * I_DIM * 2;      // act 11.5 MB
// tmp 33.5 MB; total ~53 MB

// async global->LDS, 16 B per lane; LDS dest is wave-uniform base + lane*16.
__device__ __forceinline__ void gload_lds16(const bf16* g, bf16* l)
{
    __builtin_amdgcn_global_load_lds((const __attribute__((address_space(1))) void*)g,
                                     (__attribute__((address_space(3))) void*)l,
                                     16, 0, 0);
}

#define PHASE_BAR() do { __builtin_amdgcn_sched_barrier(0); \
                         __builtin_amdgcn_s_barrier(); \
                         __builtin_amdgcn_sched_barrier(0); } while (0)

#define RD(buf, row, g8) (*reinterpret_cast<const bf16x8*>(&(buf)[(row) * 64 + (g8)]))

// ---------------- x f32 -> bf16 ----------------
__global__ void xconv_kernel(const float* __restrict__ x, bf16* __restrict__ xb)
{
    int i = blockIdx.x * blockDim.x + threadIdx.x;
    const float4* x4 = reinterpret_cast<const float4*>(x) + (size_t)i * 2;
    float4 v0 = x4[0], v1 = x4[1];
    bf16x8 bv;
    bv[0] = (bf16)v0.x; bv[1] = (bf16)v0.y; bv[2] = (bf16)v0.z; bv[3] = (bf16)v0.w;
    bv[4] = (bf16)v1.x; bv[5] = (bf16)v1.y; bv[6] = (bf16)v1.z; bv[7] = (bf16)v1.w;
    *reinterpret_cast<bf16x8*>(xb + (size_t)i * 8) = bv;
}

// ---------------- routing ----------------
__global__ void router_kernel(const float* __restrict__ logits,
                              int* __restrict__ counts,
                              int* __restrict__ lists,
                              float* __restrict__ wlists)
{
    int t = blockIdx.x * blockDim.x + threadIdx.x;
    if (t >= T_TOKENS) return;
    const float* l = logits + (size_t)t * E_NUM;
    float v0 = -1e30f, v1 = -1e30f;
    int i0 = 0, i1 = 0;
    #pragma unroll
    for (int e = 0; e < E_NUM; ++e) {
        float v = l[e];
        if (v > v0) { v1 = v0; i1 = i0; v0 = v; i0 = e; }
        else if (v > v1) { v1 = v; i1 = e; }
    }
    float w0 = 1.f / (1.f + __expf(v1 - v0));
    float w1 = 1.f - w0;
    int p0 = atomicAdd(&counts[i0], 1);
    lists[i0 * T_TOKENS + p0] = t * 2 + 0;
    wlists[i0 * T_TOKENS + p0] = w0;
    int p1 = atomicAdd(&counts[i1], 1);
    lists[i1 * T_TOKENS + p1] = t * 2 + 1;
    wlists[i1 * T_TOKENS + p1] = w1;
}

// ============== GEMM1: xb @ dequant(W_gate_up)^T, fused SwiGLU ==============
// 256 threads (4 waves, 2M x 2N), tile M=256 tokens x 128 B-rows (=64 I-cols).
// A (256x64 bf16) via global_load_lds with source pre-swizzle (linear LDS dest).
// B (128x64) dequantized in-reg from int32 q, ds_written to the swizzled layout:
// LDS slot s holds logical granule (s&7)^(row&7) of row s>>3.
// B q+scale regs are prefetched one K-tile ahead (counted vmcnt keeps them in
// flight across the barrier); A drains at the pre-MFMA barrier (round-1 regime).
__global__ __launch_bounds__(256, 2) void gemm1_kernel(
    const bf16*  __restrict__ xb,
    const int*   __restrict__ q,
    const float* __restrict__ sc,
    const int*   __restrict__ counts,
    const int*   __restrict__ lists,
    bf16*        __restrict__ act)
{
    // XCD-chunked: one expert per XCD, m-tile fastest. 1408 = 8 * 176.
    const int lid = (blockIdx.x & 7) * 176 + (blockIdx.x >> 3);
    const int e   = lid / 176;
    const int r_  = lid - e * 176;
    const int nt  = r_ >> 3;          // 0..21, 64 I-cols
    const int m0  = (r_ & 7) << 8;    // 0..1792
    const int cnt = counts[e];
    if (m0 >= cnt) return;

    __shared__ __align__(16) bf16 Al[16384];   // 256 x 64
    __shared__ __align__(16) bf16 Bl[8192];    // 128 x 64
    __shared__ int meta[256];

    const int tid = threadIdx.x;
    if (tid < 256) {
        int m = m0 + tid;
        meta[tid] = lists[e * T_TOKENS + (m < cnt ? m : 0)];
    }
    __syncthreads();

    const int lane = tid & 63;
    const int wv = tid >> 6;
    const int wm = wv >> 1, wn = wv & 1;

    const int gB = (tid & 7) ^ ((tid >> 3) & 7);   // logical granule for linear slot tid

    // A: 8 granule-slots per thread (slot = tid + 256j, row = tid>>3 + 32j)
    size_t aglb[8];
    #pragma unroll
    for (int j = 0; j < 8; ++j)
        aglb[j] = (size_t)(meta[(tid >> 3) + 32 * j] >> 1) * H_DIM + gB * 8;

    // B: 4 granules per thread (slot = tid + 256j, row = tid>>3 + 32j, j<4)
    const int*   qb_[4];
    const float* sb_[4];
    #pragma unroll
    for (int j = 0; j < 4; ++j) {
        int r     = (tid >> 3) + 32 * j;        // B-tile row 0..127
        int t16   = r >> 4;
        int is_up = t16 & 1;
        int icol  = nt * 64 + (t16 >> 1) * 16 + (r & 15);
        int row_q = e * 2816 + (is_up ? I_DIM : 0) + icol;
        qb_[j] = q  + (size_t)row_q * H_DIM + gB * 8;
        sb_[j] = sc + (size_t)row_q * 16;
    }

    floatx4 acc[8][4];
    #pragma unroll
    for (int i = 0; i < 8; ++i)
        #pragma unroll
        for (int j = 0; j < 4; ++j)
            acc[i][j] = (floatx4){0.f, 0.f, 0.f, 0.f};

    // prologue: prefetch B regs for kt=0  (8 q-loads + 4 scale loads = 12 vm)
    int4  qv[8];
    float scv[4];
    #pragma unroll
    for (int j = 0; j < 4; ++j) {
        const int4* p = reinterpret_cast<const int4*>(qb_[j]);
        qv[2 * j]     = p[0];
        qv[2 * j + 1] = p[1];
        scv[j]        = sb_[j][0];
    }

    const int l15   = lane & 15;
    const int g80   = (((lane >> 4) ^ (lane & 7)) << 3);
    const int g81   = g80 ^ 32;
    const int abase = wm * 128 + l15;
    const int bbase = wn * 64 + l15;

    for (int kt = 0; kt < 32; ++kt) {
        const int k0 = kt * 64;
        // issue A staging (8 gload_lds)
        #pragma unroll
        for (int j = 0; j < 8; ++j)
            gload_lds16(xb + aglb[j] + k0, &Al[(tid + 256 * j) * 8]);

        // wait for this tile's B regs (12 older), leave A(8) in flight
        asm volatile("s_waitcnt vmcnt(8)" ::: "memory");

        // dequant -> swizzled LDS (linear lane writes, conflict-free)
        #pragma unroll
        for (int j = 0; j < 4; ++j) {
            float s = scv[j], m8 = -8.f * s;
            int4 a = qv[2 * j], b = qv[2 * j + 1];
            bf16x8 bv;
            bv[0] = (bf16)fmaf((float)a.x, s, m8);
            bv[1] = (bf16)fmaf((float)a.y, s, m8);
            bv[2] = (bf16)fmaf((float)a.z, s, m8);
            bv[3] = (bf16)fmaf((float)a.w, s, m8);
            bv[4] = (bf16)fmaf((float)b.x, s, m8);
            bv[5] = (bf16)fmaf((float)b.y, s, m8);
            bv[6] = (bf16)fmaf((float)b.z, s, m8);
            bv[7] = (bf16)fmaf((float)b.w, s, m8);
            *reinterpret_cast<bf16x8*>(&Bl[(tid + 256 * j) * 8]) = bv;
        }

        if (kt < 31) {
            // prefetch B regs for kt+1 (12 vm), then drain A (oldest 8)
            const int koff = k0 + 64;
            const int grp  = (kt + 1) >> 1;
            #pragma unroll
            for (int j = 0; j < 4; ++j) {
                const int4* p = reinterpret_cast<const int4*>(qb_[j] + koff);
                qv[2 * j]     = p[0];
                qv[2 * j + 1] = p[1];
                scv[j]        = sb_[j][grp];
            }
            asm volatile("s_waitcnt vmcnt(12)" ::: "memory");
        } else {
            asm volatile("s_waitcnt vmcnt(0)" ::: "memory");
        }
        asm volatile("s_waitcnt lgkmcnt(0)" ::: "memory");
        PHASE_BAR();

        #pragma unroll
        for (int ks = 0; ks < 2; ++ks) {
            const int g8 = ks ? g81 : g80;
            bf16x8 bf_[4];
            #pragma unroll
            for (int nf = 0; nf < 4; ++nf)
                bf_[nf] = RD(Bl, bbase + nf * 16, g8);
            #pragma unroll
            for (int mt = 0; mt < 8; ++mt) {
                bf16x8 af = RD(Al, abase + mt * 16, g8);
                #pragma unroll
                for (int nf = 0; nf < 4; ++nf)
                    acc[mt][nf] = MFMA(af, bf_[nf], acc[mt][nf], 0, 0, 0);
            }
        }
        PHASE_BAR();
    }

    // epilogue: SwiGLU (gate = even nf, up = odd nf), scatter to act
    const int rbase = (lane >> 4) * 4;
    const int cn = lane & 15;
    #pragma unroll
    for (int mt = 0; mt < 8; ++mt) {
        #pragma unroll
        for (int qd = 0; qd < 2; ++qd) {
            floatx4 g = acc[mt][2 * qd];
            floatx4 u = acc[mt][2 * qd + 1];
            int col = nt * 64 + (wn * 2 + qd) * 16 + cn;
            #pragma unroll
            for (int r = 0; r < 4; ++r) {
                int lrow = wm * 128 + mt * 16 + rbase + r;
                if (m0 + lrow < cnt) {
                    float gate = g[r], up = u[r];
                    float av = gate / (1.f + __expf(-gate)) * up;
                    act[(size_t)meta[lrow] * I_DIM + col] = (bf16)av;
                }
            }
        }
    }
}

// ============== GEMM2: act @ dequant(W_down)^T, weighted write to tmp ==============
// Same structure; tile M=256 slots x 128 H-cols, K = 1408 (22 k-tiles).
__global__ __launch_bounds__(256, 2) void gemm2_kernel(
    const bf16*  __restrict__ act,
    const int*   __restrict__ q,
    const float* __restrict__ sc,
    const int*   __restrict__ counts,
    const int*   __restrict__ lists,
    const float* __restrict__ wlists,
    float*       __restrict__ tmp)
{
    // 1024 = 8 * 128, one expert per XCD, m-tile fastest
    const int lid = (blockIdx.x & 7) * 128 + (blockIdx.x >> 3);
    const int e   = lid >> 7;
    const int r_  = lid & 127;
    const int nt  = r_ >> 3;          // 0..15, 128 H-cols
    const int m0  = (r_ & 7) << 8;
    const int cnt = counts[e];
    if (m0 >= cnt) return;

    __shared__ __align__(16) bf16 Al[16384];
    __shared__ __align__(16) bf16 Bl[8192];
    __shared__ int   meta[256];
    __shared__ float wmeta[256];

    const int tid = threadIdx.x;
    if (tid < 256) {
        int m = m0 + tid;
        int mm = (m < cnt) ? m : 0;
        meta[tid]  = lists[e * T_TOKENS + mm];
        wmeta[tid] = wlists[e * T_TOKENS + mm];
    }
    __syncthreads();

    const int lane = tid & 63;
    const int wv = tid >> 6;
    const int wm = wv >> 1, wn = wv & 1;

    const int gB = (tid & 7) ^ ((tid >> 3) & 7);

    size_t aglb[8];
    #pragma unroll
    for (int j = 0; j < 8; ++j)
        aglb[j] = (size_t)meta[(tid >> 3) + 32 * j] * I_DIM + gB * 8;

    const int*   qb_[4];
    const float* sb_[4];
    #pragma unroll
    for (int j = 0; j < 4; ++j) {
        int r     = (tid >> 3) + 32 * j;
        int row_q = e * 2048 + nt * 128 + r;
        qb_[j] = q  + (size_t)row_q * I_DIM + gB * 8;
        sb_[j] = sc + (size_t)row_q * 11;
    }

    floatx4 acc[8][4];
    #pragma unroll
    for (int i = 0; i < 8; ++i)
        #pragma unroll
        for (int j = 0; j < 4; ++j)
            acc[i][j] = (floatx4){0.f, 0.f, 0.f, 0.f};

    int4  qv[8];
    float scv[4];
    #pragma unroll
    for (int j = 0; j < 4; ++j) {
        const int4* p = reinterpret_cast<const int4*>(qb_[j]);
        qv[2 * j]     = p[0];
        qv[2 * j + 1] = p[1];
        scv[j]        = sb_[j][0];
    }

    const int l15   = lane & 15;
    const int g80   = (((lane >> 4) ^ (lane & 7)) << 3);
    const int g81   = g80 ^ 32;
    const int abase = wm * 128 + l15;
    const int bbase = wn * 64 + l15;

    for (int kt = 0; kt < 22; ++kt) {
        const int k0 = kt * 64;
        #pragma unroll
        for (int j = 0; j < 8; ++j)
            gload_lds16(act + aglb[j] + k0, &Al[(tid + 256 * j) * 8]);

        asm volatile("s_waitcnt vmcnt(8)" ::: "memory");

        #pragma unroll
        for (int j = 0; j < 4; ++j) {
            float s = scv[j], m8 = -8.f * s;
            int4 a = qv[2 * j], b = qv[2 * j + 1];
            bf16x8 bv;
            bv[0] = (bf16)fmaf((float)a.x, s, m8);
            bv[1] = (bf16)fmaf((float)a.y, s, m8);
            bv[2] = (bf16)fmaf((float)a.z, s, m8);
            bv[3] = (bf16)fmaf((float)a.w, s, m8);
            bv[4] = (bf16)fmaf((float)b.x, s, m8);
            bv[5] = (bf16)fmaf((float)b.y, s, m8);
            bv[6] = (bf16)fmaf((float)b.z, s, m8);
            bv[7] = (bf16)fmaf((float)b.w, s, m8);
            *reinterpret_cast<bf16x8*>(&Bl[(tid + 256 * j) * 8]) = bv;
        }

        if (kt < 21) {
            const int koff = k0 + 64;
            const int grp  = (kt + 1) >> 1;
            #pragma unroll
            for (int j = 0; j < 4; ++j) {
                const int4* p = reinterpret_cast<const int4*>(qb_[j] + koff);
                qv[2 * j]     = p[0];
                qv[2 * j + 1] = p[1];
                scv[j]        = sb_[j][grp];
            }
            asm volatile("s_waitcnt vmcnt(12)" ::: "memory");
        } else {
            asm volatile("s_waitcnt vmcnt(0)" ::: "memory");
        }
        asm volatile("s_waitcnt lgkmcnt(0)" ::: "memory");
        PHASE_BAR();

        #pragma unroll
        for (int ks = 0; ks < 2; ++ks) {
            const int g8 = ks ? g81 : g80;
            bf16x8 bf_[4];
            #pragma unroll
            for (int nf = 0; nf < 4; ++nf)
                bf_[nf] = RD(Bl, bbase + nf * 16, g8);
            #pragma unroll
            for (int mt = 0; mt < 8; ++mt) {
                bf16x8 af = RD(Al, abase + mt * 16, g8);
                #pragma unroll
                for (int nf = 0; nf < 4; ++nf)
                    acc[mt][nf] = MFMA(af, bf_[nf], acc[mt][nf], 0, 0, 0);
            }
        }
        PHASE_BAR();
    }

    const int rbase = (lane >> 4) * 4;
    const int cn = lane & 15;
    #pragma unroll
    for (int mt = 0; mt < 8; ++mt) {
        #pragma unroll
        for (int nf = 0; nf < 4; ++nf) {
            floatx4 v = acc[mt][nf];
            int col = nt * 128 + wn * 64 + nf * 16 + cn;
            #pragma unroll
            for (int r = 0; r < 4; ++r) {
                int lrow = wm * 128 + mt * 16 + rbase + r;
                if (m0 + lrow < cnt) {
                    tmp[(size_t)meta[lrow] * H_DIM + col] = wmeta[lrow] * v[r];
                }
            }
        }
    }
}

// ---------------- finalize: out[t] = tmp[2t] + tmp[2t+1] ----------------
__global__ void finalize_kernel(const float* __restrict__ tmp, float* __restrict__ out)
{
    int i4 = blockIdx.x * blockDim.x + threadIdx.x;
    int t  = i4 >> 9;
    int h  = (i4 & 511) * 4;
    float4 a = *reinterpret_cast<const float4*>(tmp + ((size_t)2 * t) * H_DIM + h);
    float4 b = *reinterpret_cast<const float4*>(tmp + ((size_t)(2 * t + 1)) * H_DIM + h);
    float4 o;
    o.x = a.x + b.x; o.y = a.y + b.y; o.z = a.z + b.z; o.w = a.w + b.w;
    *reinterpret_cast<float4*>(out + (size_t)t * H_DIM + h) = o;
}

extern "C" void kernel_launch(void* const* d_in, const int* in_sizes, int n_in,
                              void* d_out, int out_size, void* d_ws, size_t ws_size,
                              hipStream_t stream)
{
    const float* router_logits = (const float*)d_in[0];
    const float* x             = (const float*)d_in[1];
    const int*   gu_q          = (const int*)d_in[2];
    const float* gu_s          = (const float*)d_in[3];
    const int*   dn_q          = (const int*)d_in[4];
    const float* dn_s          = (const float*)d_in[5];
    float* out = (float*)d_out;

    char* ws = (char*)d_ws;
    int*   counts = (int*)(ws + OFF_COUNTS);
    int*   lists  = (int*)(ws + OFF_LISTS);
    float* wlists = (float*)(ws + OFF_WLISTS);
    bf16*  xb     = (bf16*)(ws + OFF_XB);
    bf16*  act    = (bf16*)(ws + OFF_ACT);
    float* tmp    = (float*)(ws + OFF_TMP);

    hipMemsetAsync(counts, 0, E_NUM * sizeof(int), stream);

    xconv_kernel<<<T_TOKENS * H_DIM / 8 / 256, 256, 0, stream>>>(x, xb);
    router_kernel<<<T_TOKENS / 256, 256, 0, stream>>>(router_logits, counts, lists, wlists);

    gemm1_kernel<<<176 * E_NUM, 256, 0, stream>>>(xb, gu_q, gu_s, counts, lists, act);
    gemm2_kernel<<<128 * E_NUM, 256, 0, stream>>>(act, dn_q, dn_s, counts, lists, wlists, tmp);
    finalize_kernel<<<4096, 256, 0, stream>>>(tmp, out);
}

// Round 4
// 544.162 us; speedup vs baseline: 1.2743x; 1.0604x over previous
//
#include <hip/hip_runtime.h>
#include <hip/hip_bf16.h>

#define T_TOKENS 2048
#define H_DIM    2048
#define I_DIM    1408
#define E_NUM    8

typedef __bf16 bf16;
typedef __attribute__((ext_vector_type(8))) __bf16  bf16x8;
typedef __attribute__((ext_vector_type(4))) float   floatx4;

// ---------------- ws layout (bytes) ----------------
// gu_pk: [E][22 n-tiles][32 k-tiles][128 r][8 g] bf16x8, XOR-swizzled granules = 92.3 MB
// dn_pk: [E][16 n-tiles][22 k-tiles][128 r][8 g] bf16x8, swizzled              = 46.1 MB
// tmp overlaps gu_pk (gu_pk dead after gemm1; tmp written by gemm2).
static const size_t OFF_COUNTS = 0;
static const size_t OFF_LISTS  = 256;
static const size_t OFF_WLISTS = OFF_LISTS + (size_t)T_TOKENS * E_NUM * 4;       // 65792
static const size_t OFF_XB     = 131328;                                          // 8 MB
static const size_t OFF_ACT    = OFF_XB + (size_t)T_TOKENS * H_DIM * 2;           // 11.5 MB
static const size_t OFF_GUPK   = OFF_ACT + (size_t)2 * T_TOKENS * I_DIM * 2;
static const size_t OFF_DNPK   = OFF_GUPK + (size_t)E_NUM * 22 * 32 * 16384;
static const size_t OFF_TMP    = OFF_GUPK;   // 33.5 MB, overlapped

// async global->LDS, 16 B per lane; LDS dest is wave-uniform base + lane*16.
__device__ __forceinline__ void gload_lds16(const bf16* g, bf16* l)
{
    __builtin_amdgcn_global_load_lds((const __attribute__((address_space(1))) void*)g,
                                     (__attribute__((address_space(3))) void*)l,
                                     16, 0, 0);
}

// ---------------- pack gate_up (v2: one block per output tile, linear writes) ----
// Block bid = (e*22 + nt)*32 + kt. Output tile = [128 r][8 g] bf16x8 = 16 KB,
// written contiguously (slot s = tid + 256j -> byte s*16). Read side computes the
// inverse map: r = s>>3, logical granule gl = (s&7)^(r&7), row_q from the
// gate/up interleave (r = (p*2+is_up)*16 + c, icol = nt*64 + p*16 + c).
__global__ __launch_bounds__(256) void pack_gu_kernel(const int* __restrict__ q,
                                                      const float* __restrict__ sc,
                                                      bf16* __restrict__ out)
{
    const int bid = blockIdx.x;
    const int kt  = bid & 31;
    const int en  = bid >> 5;
    const int nt  = en % 22;
    const int e   = en / 22;
    const int tid = threadIdx.x;
    bf16x8* ob = reinterpret_cast<bf16x8*>(out) + (size_t)bid * 1024;
    #pragma unroll
    for (int j = 0; j < 4; ++j) {
        const int s     = tid + 256 * j;
        const int r     = s >> 3;
        const int gl    = (s & 7) ^ (r & 7);
        const int p2    = r >> 4;
        const int is_up = p2 & 1;
        const int icol  = nt * 64 + (p2 >> 1) * 16 + (r & 15);
        const size_t row_q = (size_t)e * 2816 + (is_up ? I_DIM : 0) + icol;
        const int4* qp = reinterpret_cast<const int4*>(q + row_q * H_DIM + kt * 64 + gl * 8);
        int4 a = qp[0], c = qp[1];
        float sv = sc[row_q * 16 + (kt >> 1)];
        float m8 = -8.f * sv;
        bf16x8 bv;
        bv[0] = (bf16)fmaf((float)a.x, sv, m8);
        bv[1] = (bf16)fmaf((float)a.y, sv, m8);
        bv[2] = (bf16)fmaf((float)a.z, sv, m8);
        bv[3] = (bf16)fmaf((float)a.w, sv, m8);
        bv[4] = (bf16)fmaf((float)c.x, sv, m8);
        bv[5] = (bf16)fmaf((float)c.y, sv, m8);
        bv[6] = (bf16)fmaf((float)c.z, sv, m8);
        bv[7] = (bf16)fmaf((float)c.w, sv, m8);
        ob[s] = bv;
    }
}

// ---------------- pack down (v2: linear writes) ----------------
// Block bid = (e*16 + nt)*22 + kt. Tile [128 r][8 g], row_q = e*2048 + nt*128 + r.
__global__ __launch_bounds__(256) void pack_dn_kernel(const int* __restrict__ q,
                                                      const float* __restrict__ sc,
                                                      bf16* __restrict__ out)
{
    const int bid = blockIdx.x;
    const int kt  = bid % 22;
    const int en  = bid / 22;
    const int nt  = en & 15;
    const int e   = en >> 4;
    const int tid = threadIdx.x;
    bf16x8* ob = reinterpret_cast<bf16x8*>(out) + (size_t)bid * 1024;
    #pragma unroll
    for (int j = 0; j < 4; ++j) {
        const int s  = tid + 256 * j;
        const int r  = s >> 3;
        const int gl = (s & 7) ^ (r & 7);
        const size_t row_q = (size_t)e * 2048 + nt * 128 + r;
        const int4* qp = reinterpret_cast<const int4*>(q + row_q * I_DIM + kt * 64 + gl * 8);
        int4 a = qp[0], c = qp[1];
        float sv = sc[row_q * 11 + (kt >> 1)];
        float m8 = -8.f * sv;
        bf16x8 bv;
        bv[0] = (bf16)fmaf((float)a.x, sv, m8);
        bv[1] = (bf16)fmaf((float)a.y, sv, m8);
        bv[2] = (bf16)fmaf((float)a.z, sv, m8);
        bv[3] = (bf16)fmaf((float)a.w, sv, m8);
        bv[4] = (bf16)fmaf((float)c.x, sv, m8);
        bv[5] = (bf16)fmaf((float)c.y, sv, m8);
        bv[6] = (bf16)fmaf((float)c.z, sv, m8);
        bv[7] = (bf16)fmaf((float)c.w, sv, m8);
        ob[s] = bv;
    }
}

// ---------------- x f32 -> bf16 ----------------
__global__ void xconv_kernel(const float* __restrict__ x, bf16* __restrict__ xb)
{
    int i = blockIdx.x * blockDim.x + threadIdx.x;
    const float4* x4 = reinterpret_cast<const float4*>(x) + (size_t)i * 2;
    float4 v0 = x4[0], v1 = x4[1];
    bf16x8 bv;
    bv[0] = (bf16)v0.x; bv[1] = (bf16)v0.y; bv[2] = (bf16)v0.z; bv[3] = (bf16)v0.w;
    bv[4] = (bf16)v1.x; bv[5] = (bf16)v1.y; bv[6] = (bf16)v1.z; bv[7] = (bf16)v1.w;
    *reinterpret_cast<bf16x8*>(xb + (size_t)i * 8) = bv;
}

// ---------------- routing ----------------
__global__ void router_kernel(const float* __restrict__ logits,
                              int* __restrict__ counts,
                              int* __restrict__ lists,
                              float* __restrict__ wlists)
{
    int t = blockIdx.x * blockDim.x + threadIdx.x;
    if (t >= T_TOKENS) return;
    const float* l = logits + (size_t)t * E_NUM;
    float v0 = -1e30f, v1 = -1e30f;
    int i0 = 0, i1 = 0;
    #pragma unroll
    for (int e = 0; e < E_NUM; ++e) {
        float v = l[e];
        if (v > v0) { v1 = v0; i1 = i0; v0 = v; i0 = e; }
        else if (v > v1) { v1 = v; i1 = e; }
    }
    float w0 = 1.f / (1.f + __expf(v1 - v0));
    float w1 = 1.f - w0;
    int p0 = atomicAdd(&counts[i0], 1);
    lists[i0 * T_TOKENS + p0] = t * 2 + 0;
    wlists[i0 * T_TOKENS + p0] = w0;
    int p1 = atomicAdd(&counts[i1], 1);
    lists[i1 * T_TOKENS + p1] = t * 2 + 1;
    wlists[i1 * T_TOKENS + p1] = w1;
}

// ---------------- GEMM1: xb @ W_gate_up^T, fused SwiGLU (round-1 verified) ----------------
__global__ __launch_bounds__(256) void gemm1_kernel(
    const bf16* __restrict__ xb,
    const bf16* __restrict__ wpk,
    const int*  __restrict__ counts,
    const int*  __restrict__ lists,
    bf16*       __restrict__ act)
{
    const int lid = (blockIdx.x & 7) * 352 + (blockIdx.x >> 3);
    const int e   = lid / 352;
    const int r_  = lid - e * 352;
    const int nt  = r_ >> 4;         // 0..21, 64 I-cols per tile
    const int m0  = (r_ & 15) * 128;
    const int cnt = counts[e];
    if (m0 >= cnt) return;

    __shared__ __align__(16) bf16 Al[8192];
    __shared__ __align__(16) bf16 Bl[8192];
    __shared__ int meta[128];

    const int tid = threadIdx.x;
    if (tid < 128) {
        int m = m0 + tid;
        meta[tid] = lists[e * T_TOKENS + (m < cnt ? m : 0)];
    }
    __syncthreads();

    const int lane = tid & 63;
    const int wv = tid >> 6;
    const int wm = wv >> 1, wn = wv & 1;

    size_t agbl[4];
    #pragma unroll
    for (int j = 0; j < 4; ++j) {
        int g = tid + 256 * j;
        int arow = g >> 3, cg = g & 7;
        agbl[j] = (size_t)(meta[arow] >> 1) * H_DIM + ((cg ^ (arow & 7)) * 8);
    }
    const bf16* bt = wpk + ((size_t)e * 22 + nt) * (32 * 8192) + tid * 8;

    int afr[2][4], bfr[2][4];
    #pragma unroll
    for (int ks = 0; ks < 2; ++ks) {
        int gidx = ks * 4 + (lane >> 4);
        #pragma unroll
        for (int t4 = 0; t4 < 4; ++t4) {
            int ra = wm * 64 + t4 * 16 + (lane & 15);
            afr[ks][t4] = ra * 64 + ((gidx ^ (ra & 7)) * 8);
            int rb = wn * 64 + t4 * 16 + (lane & 15);
            bfr[ks][t4] = rb * 64 + ((gidx ^ (rb & 7)) * 8);
        }
    }

    floatx4 acc[4][4];
    #pragma unroll
    for (int i = 0; i < 4; ++i)
        #pragma unroll
        for (int j = 0; j < 4; ++j)
            acc[i][j] = (floatx4){0.f, 0.f, 0.f, 0.f};

    for (int k0 = 0; k0 < H_DIM; k0 += 64) {
        #pragma unroll
        for (int j = 0; j < 4; ++j)
            gload_lds16(xb + agbl[j] + k0, &Al[(tid + 256 * j) * 8]);
        const bf16* bsrc = bt + (size_t)(k0 >> 6) * 8192;
        #pragma unroll
        for (int j = 0; j < 4; ++j)
            gload_lds16(bsrc + j * 2048, &Bl[tid * 8 + j * 2048]);
        __syncthreads();
        #pragma unroll
        for (int ks = 0; ks < 2; ++ks) {
            bf16x8 af[4], bff[4];
            #pragma unroll
            for (int mt = 0; mt < 4; ++mt)
                af[mt] = *reinterpret_cast<const bf16x8*>(&Al[afr[ks][mt]]);
            #pragma unroll
            for (int ntf = 0; ntf < 4; ++ntf)
                bff[ntf] = *reinterpret_cast<const bf16x8*>(&Bl[bfr[ks][ntf]]);
            #pragma unroll
            for (int mt = 0; mt < 4; ++mt)
                #pragma unroll
                for (int ntf = 0; ntf < 4; ++ntf)
                    acc[mt][ntf] = __builtin_amdgcn_mfma_f32_16x16x32_bf16(af[mt], bff[ntf], acc[mt][ntf], 0, 0, 0);
        }
        __syncthreads();
    }

    const int rbase = (lane >> 4) * 4;
    const int cn = lane & 15;
    #pragma unroll
    for (int mt = 0; mt < 4; ++mt) {
        #pragma unroll
        for (int j = 0; j < 2; ++j) {
            floatx4 g = acc[mt][2 * j];
            floatx4 u = acc[mt][2 * j + 1];
            int col = nt * 64 + (wn * 2 + j) * 16 + cn;
            #pragma unroll
            for (int r = 0; r < 4; ++r) {
                int lrow = wm * 64 + mt * 16 + rbase + r;
                if (m0 + lrow < cnt) {
                    float gate = g[r], up = u[r];
                    float a = gate / (1.f + __expf(-gate)) * up;
                    act[(size_t)meta[lrow] * I_DIM + col] = (bf16)a;
                }
            }
        }
    }
}

// ---------------- GEMM2: act @ W_down^T, weighted write to tmp ----------------
__global__ __launch_bounds__(256) void gemm2_kernel(
    const bf16*  __restrict__ act,
    const bf16*  __restrict__ wpk,
    const int*   __restrict__ counts,
    const int*   __restrict__ lists,
    const float* __restrict__ wlists,
    float*       __restrict__ tmp)
{
    const int lid = (blockIdx.x & 7) * 256 + (blockIdx.x >> 3);
    const int e   = lid >> 8;
    const int r_  = lid & 255;
    const int nt  = r_ >> 4;        // 0..15, 128 H-cols per tile
    const int m0  = (r_ & 15) * 128;
    const int cnt = counts[e];
    if (m0 >= cnt) return;

    __shared__ __align__(16) bf16 Al[8192];
    __shared__ __align__(16) bf16 Bl[8192];
    __shared__ int   meta[128];
    __shared__ float wmeta[128];

    const int tid = threadIdx.x;
    if (tid < 128) {
        int m = m0 + tid;
        int mm = (m < cnt) ? m : 0;
        meta[tid]  = lists[e * T_TOKENS + mm];
        wmeta[tid] = wlists[e * T_TOKENS + mm];
    }
    __syncthreads();

    const int lane = tid & 63;
    const int wv = tid >> 6;
    const int wm = wv >> 1, wn = wv & 1;

    size_t agbl[4];
    #pragma unroll
    for (int j = 0; j < 4; ++j) {
        int g = tid + 256 * j;
        int arow = g >> 3, cg = g & 7;
        agbl[j] = (size_t)meta[arow] * I_DIM + ((cg ^ (arow & 7)) * 8);
    }
    const bf16* bt = wpk + ((size_t)e * 16 + nt) * (22 * 8192) + tid * 8;

    int afr[2][4], bfr[2][4];
    #pragma unroll
    for (int ks = 0; ks < 2; ++ks) {
        int gidx = ks * 4 + (lane >> 4);
        #pragma unroll
        for (int t4 = 0; t4 < 4; ++t4) {
            int ra = wm * 64 + t4 * 16 + (lane & 15);
            afr[ks][t4] = ra * 64 + ((gidx ^ (ra & 7)) * 8);
            int rb = wn * 64 + t4 * 16 + (lane & 15);
            bfr[ks][t4] = rb * 64 + ((gidx ^ (rb & 7)) * 8);
        }
    }

    floatx4 acc[4][4];
    #pragma unroll
    for (int i = 0; i < 4; ++i)
        #pragma unroll
        for (int j = 0; j < 4; ++j)
            acc[i][j] = (floatx4){0.f, 0.f, 0.f, 0.f};

    for (int kt = 0; kt < 22; ++kt) {
        #pragma unroll
        for (int j = 0; j < 4; ++j)
            gload_lds16(act + agbl[j] + kt * 64, &Al[(tid + 256 * j) * 8]);
        const bf16* bsrc = bt + (size_t)kt * 8192;
        #pragma unroll
        for (int j = 0; j < 4; ++j)
            gload_lds16(bsrc + j * 2048, &Bl[tid * 8 + j * 2048]);
        __syncthreads();
        #pragma unroll
        for (int ks = 0; ks < 2; ++ks) {
            bf16x8 af[4], bff[4];
            #pragma unroll
            for (int mt = 0; mt < 4; ++mt)
                af[mt] = *reinterpret_cast<const bf16x8*>(&Al[afr[ks][mt]]);
            #pragma unroll
            for (int ntf = 0; ntf < 4; ++ntf)
                bff[ntf] = *reinterpret_cast<const bf16x8*>(&Bl[bfr[ks][ntf]]);
            #pragma unroll
            for (int mt = 0; mt < 4; ++mt)
                #pragma unroll
                for (int ntf = 0; ntf < 4; ++ntf)
                    acc[mt][ntf] = __builtin_amdgcn_mfma_f32_16x16x32_bf16(af[mt], bff[ntf], acc[mt][ntf], 0, 0, 0);
        }
        __syncthreads();
    }

    const int rbase = (lane >> 4) * 4;
    const int cn = lane & 15;
    #pragma unroll
    for (int mt = 0; mt < 4; ++mt) {
        #pragma unroll
        for (int ntf = 0; ntf < 4; ++ntf) {
            floatx4 v = acc[mt][ntf];
            int col = nt * 128 + wn * 64 + ntf * 16 + cn;
            #pragma unroll
            for (int r = 0; r < 4; ++r) {
                int lrow = wm * 64 + mt * 16 + rbase + r;
                if (m0 + lrow < cnt) {
                    tmp[(size_t)meta[lrow] * H_DIM + col] = wmeta[lrow] * v[r];
                }
            }
        }
    }
}

// ---------------- finalize: out[t] = tmp[2t] + tmp[2t+1] ----------------
__global__ void finalize_kernel(const float* __restrict__ tmp, float* __restrict__ out)
{
    int i4 = blockIdx.x * blockDim.x + threadIdx.x;
    int t  = i4 >> 9;
    int h  = (i4 & 511) * 4;
    float4 a = *reinterpret_cast<const float4*>(tmp + ((size_t)2 * t) * H_DIM + h);
    float4 b = *reinterpret_cast<const float4*>(tmp + ((size_t)(2 * t + 1)) * H_DIM + h);
    float4 o;
    o.x = a.x + b.x; o.y = a.y + b.y; o.z = a.z + b.z; o.w = a.w + b.w;
    *reinterpret_cast<float4*>(out + (size_t)t * H_DIM + h) = o;
}

extern "C" void kernel_launch(void* const* d_in, const int* in_sizes, int n_in,
                              void* d_out, int out_size, void* d_ws, size_t ws_size,
                              hipStream_t stream)
{
    const float* router_logits = (const float*)d_in[0];
    const float* x             = (const float*)d_in[1];
    const int*   gu_q          = (const int*)d_in[2];
    const float* gu_s          = (const float*)d_in[3];
    const int*   dn_q          = (const int*)d_in[4];
    const float* dn_s          = (const float*)d_in[5];
    float* out = (float*)d_out;

    char* ws = (char*)d_ws;
    int*   counts = (int*)(ws + OFF_COUNTS);
    int*   lists  = (int*)(ws + OFF_LISTS);
    float* wlists = (float*)(ws + OFF_WLISTS);
    bf16*  xb     = (bf16*)(ws + OFF_XB);
    bf16*  act    = (bf16*)(ws + OFF_ACT);
    bf16*  gu_pk  = (bf16*)(ws + OFF_GUPK);
    bf16*  dn_pk  = (bf16*)(ws + OFF_DNPK);
    float* tmp    = (float*)(ws + OFF_TMP);   // overlaps gu_pk (dead after gemm1)

    hipMemsetAsync(counts, 0, E_NUM * sizeof(int), stream);

    pack_gu_kernel<<<E_NUM * 22 * 32, 256, 0, stream>>>(gu_q, gu_s, gu_pk);
    pack_dn_kernel<<<E_NUM * 16 * 22, 256, 0, stream>>>(dn_q, dn_s, dn_pk);
    xconv_kernel<<<T_TOKENS * H_DIM / 8 / 256, 256, 0, stream>>>(x, xb);
    router_kernel<<<T_TOKENS / 256, 256, 0, stream>>>(router_logits, counts, lists, wlists);

    gemm1_kernel<<<22 * 16 * E_NUM, 256, 0, stream>>>(xb, gu_pk, counts, lists, act);
    gemm2_kernel<<<16 * 16 * E_NUM, 256, 0, stream>>>(act, dn_pk, counts, lists, wlists, tmp);
    finalize_kernel<<<4096, 256, 0, stream>>>(tmp, out);
}

// Round 5
// 510.821 us; speedup vs baseline: 1.3575x; 1.0653x over previous
//
#include <hip/hip_runtime.h>
#include <hip/hip_bf16.h>

#define T_TOKENS 2048
#define H_DIM    2048
#define I_DIM    1408
#define E_NUM    8

typedef __bf16 bf16;
typedef __attribute__((ext_vector_type(8))) __bf16  bf16x8;
typedef __attribute__((ext_vector_type(4))) float   floatx4;

// ---------------- ws layout (bytes) ----------------
// gu_pk: [E][22 n-tiles][32 k-tiles][128 r][8 g] bf16x8, XOR-swizzled granules = 92.3 MB
// dn_pk: [E][16 n-tiles][22 k-tiles][128 r][8 g] bf16x8, swizzled              = 46.1 MB
// tmp overlaps gu_pk (gu_pk dead after gemm1; tmp written by gemm2).
static const size_t OFF_COUNTS = 0;
static const size_t OFF_LISTS  = 256;
static const size_t OFF_WLISTS = OFF_LISTS + (size_t)T_TOKENS * E_NUM * 4;       // 65792
static const size_t OFF_XB     = 131328;                                          // 8 MB
static const size_t OFF_ACT    = OFF_XB + (size_t)T_TOKENS * H_DIM * 2;           // 11.5 MB
static const size_t OFF_GUPK   = OFF_ACT + (size_t)2 * T_TOKENS * I_DIM * 2;
static const size_t OFF_DNPK   = OFF_GUPK + (size_t)E_NUM * 22 * 32 * 16384;
static const size_t OFF_TMP    = OFF_GUPK;   // 33.5 MB, overlapped

// async global->LDS, 16 B per lane; LDS dest is wave-uniform base + lane*16.
__device__ __forceinline__ void gload_lds16(const bf16* g, bf16* l)
{
    __builtin_amdgcn_global_load_lds((const __attribute__((address_space(1))) void*)g,
                                     (__attribute__((address_space(3))) void*)l,
                                     16, 0, 0);
}

// ================= K1: prep = pack_gu (5632) + xconv (2048) + router (8) =================
// All three are mutually independent and BW-bound; fusing them into one grid lets
// them share the memory system instead of serializing on the stream.
__global__ __launch_bounds__(256) void prep_kernel(
    const int*   __restrict__ gu_q,
    const float* __restrict__ gu_s,
    bf16*        __restrict__ gu_pk,
    const float* __restrict__ x,
    bf16*        __restrict__ xb,
    const float* __restrict__ logits,
    int*         __restrict__ counts,
    int*         __restrict__ lists,
    float*       __restrict__ wlists)
{
    const int bid = blockIdx.x;
    const int tid = threadIdx.x;

    if (bid < 5632) {
        // ---- pack_gu v2: one block per output tile, linear 16 KB writes ----
        const int kt  = bid & 31;
        const int en  = bid >> 5;
        const int nt  = en % 22;
        const int e   = en / 22;
        bf16x8* ob = reinterpret_cast<bf16x8*>(gu_pk) + (size_t)bid * 1024;
        #pragma unroll
        for (int j = 0; j < 4; ++j) {
            const int s     = tid + 256 * j;
            const int r     = s >> 3;
            const int gl    = (s & 7) ^ (r & 7);
            const int p2    = r >> 4;
            const int is_up = p2 & 1;
            const int icol  = nt * 64 + (p2 >> 1) * 16 + (r & 15);
            const size_t row_q = (size_t)e * 2816 + (is_up ? I_DIM : 0) + icol;
            const int4* qp = reinterpret_cast<const int4*>(gu_q + row_q * H_DIM + kt * 64 + gl * 8);
            int4 a = qp[0], c = qp[1];
            float sv = gu_s[row_q * 16 + (kt >> 1)];
            float m8 = -8.f * sv;
            bf16x8 bv;
            bv[0] = (bf16)fmaf((float)a.x, sv, m8);
            bv[1] = (bf16)fmaf((float)a.y, sv, m8);
            bv[2] = (bf16)fmaf((float)a.z, sv, m8);
            bv[3] = (bf16)fmaf((float)a.w, sv, m8);
            bv[4] = (bf16)fmaf((float)c.x, sv, m8);
            bv[5] = (bf16)fmaf((float)c.y, sv, m8);
            bv[6] = (bf16)fmaf((float)c.z, sv, m8);
            bv[7] = (bf16)fmaf((float)c.w, sv, m8);
            ob[s] = bv;
        }
    } else if (bid < 5632 + 2048) {
        // ---- xconv: f32 -> bf16, 8 elems/thread ----
        const int i = (bid - 5632) * 256 + tid;
        const float4* x4 = reinterpret_cast<const float4*>(x) + (size_t)i * 2;
        float4 v0 = x4[0], v1 = x4[1];
        bf16x8 bv;
        bv[0] = (bf16)v0.x; bv[1] = (bf16)v0.y; bv[2] = (bf16)v0.z; bv[3] = (bf16)v0.w;
        bv[4] = (bf16)v1.x; bv[5] = (bf16)v1.y; bv[6] = (bf16)v1.z; bv[7] = (bf16)v1.w;
        *reinterpret_cast<bf16x8*>(xb + (size_t)i * 8) = bv;
    } else {
        // ---- router ----
        const int t = (bid - 7680) * 256 + tid;
        const float* l = logits + (size_t)t * E_NUM;
        float v0 = -1e30f, v1 = -1e30f;
        int i0 = 0, i1 = 0;
        #pragma unroll
        for (int e = 0; e < E_NUM; ++e) {
            float v = l[e];
            if (v > v0) { v1 = v0; i1 = i0; v0 = v; i0 = e; }
            else if (v > v1) { v1 = v; i1 = e; }
        }
        float w0 = 1.f / (1.f + __expf(v1 - v0));
        float w1 = 1.f - w0;
        int p0 = atomicAdd(&counts[i0], 1);
        lists[i0 * T_TOKENS + p0] = t * 2 + 0;
        wlists[i0 * T_TOKENS + p0] = w0;
        int p1 = atomicAdd(&counts[i1], 1);
        lists[i1 * T_TOKENS + p1] = t * 2 + 1;
        wlists[i1 * T_TOKENS + p1] = w1;
    }
}

// ================= K2: gemm1 (blocks 0..2815) + pack_dn (2816..5631) =================
// pack_dn is needed only by gemm2, so it co-resides with gemm1: ~75% of gemm1
// blocks early-exit (m0 >= cnt), freeing slots; pack_dn's pure-BW work fills
// gemm1's idle bandwidth and issue slots. Contiguous ranges keep gemm1's
// bid&7 -> XCD expert pinning intact.
__global__ __launch_bounds__(256) void gemm1_packdn_kernel(
    const bf16*  __restrict__ xb,
    const bf16*  __restrict__ wpk,
    const int*   __restrict__ counts,
    const int*   __restrict__ lists,
    bf16*        __restrict__ act,
    const int*   __restrict__ dn_q,
    const float* __restrict__ dn_s,
    bf16*        __restrict__ dn_pk)
{
    const int tid = threadIdx.x;

    if (blockIdx.x >= 2816) {
        // ---- pack_dn v2: linear writes ----
        const int pbid = blockIdx.x - 2816;
        const int kt  = pbid % 22;
        const int en  = pbid / 22;
        const int nt  = en & 15;
        const int e   = en >> 4;
        bf16x8* ob = reinterpret_cast<bf16x8*>(dn_pk) + (size_t)pbid * 1024;
        #pragma unroll
        for (int j = 0; j < 4; ++j) {
            const int s  = tid + 256 * j;
            const int r  = s >> 3;
            const int gl = (s & 7) ^ (r & 7);
            const size_t row_q = (size_t)e * 2048 + nt * 128 + r;
            const int4* qp = reinterpret_cast<const int4*>(dn_q + row_q * I_DIM + kt * 64 + gl * 8);
            int4 a = qp[0], c = qp[1];
            float sv = dn_s[row_q * 11 + (kt >> 1)];
            float m8 = -8.f * sv;
            bf16x8 bv;
            bv[0] = (bf16)fmaf((float)a.x, sv, m8);
            bv[1] = (bf16)fmaf((float)a.y, sv, m8);
            bv[2] = (bf16)fmaf((float)a.z, sv, m8);
            bv[3] = (bf16)fmaf((float)a.w, sv, m8);
            bv[4] = (bf16)fmaf((float)c.x, sv, m8);
            bv[5] = (bf16)fmaf((float)c.y, sv, m8);
            bv[6] = (bf16)fmaf((float)c.z, sv, m8);
            bv[7] = (bf16)fmaf((float)c.w, sv, m8);
            ob[s] = bv;
        }
        return;
    }

    // ---- gemm1 (round-1/4 verified): xb @ W_gate_up^T, fused SwiGLU ----
    const int lid = (blockIdx.x & 7) * 352 + (blockIdx.x >> 3);
    const int e   = lid / 352;
    const int r_  = lid - e * 352;
    const int nt  = r_ >> 4;         // 0..21, 64 I-cols per tile
    const int m0  = (r_ & 15) * 128;
    const int cnt = counts[e];
    if (m0 >= cnt) return;

    __shared__ __align__(16) bf16 Al[8192];
    __shared__ __align__(16) bf16 Bl[8192];
    __shared__ int meta[128];

    if (tid < 128) {
        int m = m0 + tid;
        meta[tid] = lists[e * T_TOKENS + (m < cnt ? m : 0)];
    }
    __syncthreads();

    const int lane = tid & 63;
    const int wv = tid >> 6;
    const int wm = wv >> 1, wn = wv & 1;

    size_t agbl[4];
    #pragma unroll
    for (int j = 0; j < 4; ++j) {
        int g = tid + 256 * j;
        int arow = g >> 3, cg = g & 7;
        agbl[j] = (size_t)(meta[arow] >> 1) * H_DIM + ((cg ^ (arow & 7)) * 8);
    }
    const bf16* bt = wpk + ((size_t)e * 22 + nt) * (32 * 8192) + tid * 8;

    int afr[2][4], bfr[2][4];
    #pragma unroll
    for (int ks = 0; ks < 2; ++ks) {
        int gidx = ks * 4 + (lane >> 4);
        #pragma unroll
        for (int t4 = 0; t4 < 4; ++t4) {
            int ra = wm * 64 + t4 * 16 + (lane & 15);
            afr[ks][t4] = ra * 64 + ((gidx ^ (ra & 7)) * 8);
            int rb = wn * 64 + t4 * 16 + (lane & 15);
            bfr[ks][t4] = rb * 64 + ((gidx ^ (rb & 7)) * 8);
        }
    }

    floatx4 acc[4][4];
    #pragma unroll
    for (int i = 0; i < 4; ++i)
        #pragma unroll
        for (int j = 0; j < 4; ++j)
            acc[i][j] = (floatx4){0.f, 0.f, 0.f, 0.f};

    for (int k0 = 0; k0 < H_DIM; k0 += 64) {
        #pragma unroll
        for (int j = 0; j < 4; ++j)
            gload_lds16(xb + agbl[j] + k0, &Al[(tid + 256 * j) * 8]);
        const bf16* bsrc = bt + (size_t)(k0 >> 6) * 8192;
        #pragma unroll
        for (int j = 0; j < 4; ++j)
            gload_lds16(bsrc + j * 2048, &Bl[tid * 8 + j * 2048]);
        __syncthreads();
        #pragma unroll
        for (int ks = 0; ks < 2; ++ks) {
            bf16x8 af[4], bff[4];
            #pragma unroll
            for (int mt = 0; mt < 4; ++mt)
                af[mt] = *reinterpret_cast<const bf16x8*>(&Al[afr[ks][mt]]);
            #pragma unroll
            for (int ntf = 0; ntf < 4; ++ntf)
                bff[ntf] = *reinterpret_cast<const bf16x8*>(&Bl[bfr[ks][ntf]]);
            #pragma unroll
            for (int mt = 0; mt < 4; ++mt)
                #pragma unroll
                for (int ntf = 0; ntf < 4; ++ntf)
                    acc[mt][ntf] = __builtin_amdgcn_mfma_f32_16x16x32_bf16(af[mt], bff[ntf], acc[mt][ntf], 0, 0, 0);
        }
        __syncthreads();
    }

    const int rbase = (lane >> 4) * 4;
    const int cn = lane & 15;
    #pragma unroll
    for (int mt = 0; mt < 4; ++mt) {
        #pragma unroll
        for (int j = 0; j < 2; ++j) {
            floatx4 g = acc[mt][2 * j];
            floatx4 u = acc[mt][2 * j + 1];
            int col = nt * 64 + (wn * 2 + j) * 16 + cn;
            #pragma unroll
            for (int r = 0; r < 4; ++r) {
                int lrow = wm * 64 + mt * 16 + rbase + r;
                if (m0 + lrow < cnt) {
                    float gate = g[r], up = u[r];
                    float a = gate / (1.f + __expf(-gate)) * up;
                    act[(size_t)meta[lrow] * I_DIM + col] = (bf16)a;
                }
            }
        }
    }
}

// ---------------- GEMM2: act @ W_down^T, weighted write to tmp ----------------
__global__ __launch_bounds__(256) void gemm2_kernel(
    const bf16*  __restrict__ act,
    const bf16*  __restrict__ wpk,
    const int*   __restrict__ counts,
    const int*   __restrict__ lists,
    const float* __restrict__ wlists,
    float*       __restrict__ tmp)
{
    const int lid = (blockIdx.x & 7) * 256 + (blockIdx.x >> 3);
    const int e   = lid >> 8;
    const int r_  = lid & 255;
    const int nt  = r_ >> 4;        // 0..15, 128 H-cols per tile
    const int m0  = (r_ & 15) * 128;
    const int cnt = counts[e];
    if (m0 >= cnt) return;

    __shared__ __align__(16) bf16 Al[8192];
    __shared__ __align__(16) bf16 Bl[8192];
    __shared__ int   meta[128];
    __shared__ float wmeta[128];

    const int tid = threadIdx.x;
    if (tid < 128) {
        int m = m0 + tid;
        int mm = (m < cnt) ? m : 0;
        meta[tid]  = lists[e * T_TOKENS + mm];
        wmeta[tid] = wlists[e * T_TOKENS + mm];
    }
    __syncthreads();

    const int lane = tid & 63;
    const int wv = tid >> 6;
    const int wm = wv >> 1, wn = wv & 1;

    size_t agbl[4];
    #pragma unroll
    for (int j = 0; j < 4; ++j) {
        int g = tid + 256 * j;
        int arow = g >> 3, cg = g & 7;
        agbl[j] = (size_t)meta[arow] * I_DIM + ((cg ^ (arow & 7)) * 8);
    }
    const bf16* bt = wpk + ((size_t)e * 16 + nt) * (22 * 8192) + tid * 8;

    int afr[2][4], bfr[2][4];
    #pragma unroll
    for (int ks = 0; ks < 2; ++ks) {
        int gidx = ks * 4 + (lane >> 4);
        #pragma unroll
        for (int t4 = 0; t4 < 4; ++t4) {
            int ra = wm * 64 + t4 * 16 + (lane & 15);
            afr[ks][t4] = ra * 64 + ((gidx ^ (ra & 7)) * 8);
            int rb = wn * 64 + t4 * 16 + (lane & 15);
            bfr[ks][t4] = rb * 64 + ((gidx ^ (rb & 7)) * 8);
        }
    }

    floatx4 acc[4][4];
    #pragma unroll
    for (int i = 0; i < 4; ++i)
        #pragma unroll
        for (int j = 0; j < 4; ++j)
            acc[i][j] = (floatx4){0.f, 0.f, 0.f, 0.f};

    for (int kt = 0; kt < 22; ++kt) {
        #pragma unroll
        for (int j = 0; j < 4; ++j)
            gload_lds16(act + agbl[j] + kt * 64, &Al[(tid + 256 * j) * 8]);
        const bf16* bsrc = bt + (size_t)kt * 8192;
        #pragma unroll
        for (int j = 0; j < 4; ++j)
            gload_lds16(bsrc + j * 2048, &Bl[tid * 8 + j * 2048]);
        __syncthreads();
        #pragma unroll
        for (int ks = 0; ks < 2; ++ks) {
            bf16x8 af[4], bff[4];
            #pragma unroll
            for (int mt = 0; mt < 4; ++mt)
                af[mt] = *reinterpret_cast<const bf16x8*>(&Al[afr[ks][mt]]);
            #pragma unroll
            for (int ntf = 0; ntf < 4; ++ntf)
                bff[ntf] = *reinterpret_cast<const bf16x8*>(&Bl[bfr[ks][ntf]]);
            #pragma unroll
            for (int mt = 0; mt < 4; ++mt)
                #pragma unroll
                for (int ntf = 0; ntf < 4; ++ntf)
                    acc[mt][ntf] = __builtin_amdgcn_mfma_f32_16x16x32_bf16(af[mt], bff[ntf], acc[mt][ntf], 0, 0, 0);
        }
        __syncthreads();
    }

    const int rbase = (lane >> 4) * 4;
    const int cn = lane & 15;
    #pragma unroll
    for (int mt = 0; mt < 4; ++mt) {
        #pragma unroll
        for (int ntf = 0; ntf < 4; ++ntf) {
            floatx4 v = acc[mt][ntf];
            int col = nt * 128 + wn * 64 + ntf * 16 + cn;
            #pragma unroll
            for (int r = 0; r < 4; ++r) {
                int lrow = wm * 64 + mt * 16 + rbase + r;
                if (m0 + lrow < cnt) {
                    tmp[(size_t)meta[lrow] * H_DIM + col] = wmeta[lrow] * v[r];
                }
            }
        }
    }
}

// ---------------- finalize: out[t] = tmp[2t] + tmp[2t+1] ----------------
__global__ void finalize_kernel(const float* __restrict__ tmp, float* __restrict__ out)
{
    int i4 = blockIdx.x * blockDim.x + threadIdx.x;
    int t  = i4 >> 9;
    int h  = (i4 & 511) * 4;
    float4 a = *reinterpret_cast<const float4*>(tmp + ((size_t)2 * t) * H_DIM + h);
    float4 b = *reinterpret_cast<const float4*>(tmp + ((size_t)(2 * t + 1)) * H_DIM + h);
    float4 o;
    o.x = a.x + b.x; o.y = a.y + b.y; o.z = a.z + b.z; o.w = a.w + b.w;
    *reinterpret_cast<float4*>(out + (size_t)t * H_DIM + h) = o;
}

extern "C" void kernel_launch(void* const* d_in, const int* in_sizes, int n_in,
                              void* d_out, int out_size, void* d_ws, size_t ws_size,
                              hipStream_t stream)
{
    const float* router_logits = (const float*)d_in[0];
    const float* x             = (const float*)d_in[1];
    const int*   gu_q          = (const int*)d_in[2];
    const float* gu_s          = (const float*)d_in[3];
    const int*   dn_q          = (const int*)d_in[4];
    const float* dn_s          = (const float*)d_in[5];
    float* out = (float*)d_out;

    char* ws = (char*)d_ws;
    int*   counts = (int*)(ws + OFF_COUNTS);
    int*   lists  = (int*)(ws + OFF_LISTS);
    float* wlists = (float*)(ws + OFF_WLISTS);
    bf16*  xb     = (bf16*)(ws + OFF_XB);
    bf16*  act    = (bf16*)(ws + OFF_ACT);
    bf16*  gu_pk  = (bf16*)(ws + OFF_GUPK);
    bf16*  dn_pk  = (bf16*)(ws + OFF_DNPK);
    float* tmp    = (float*)(ws + OFF_TMP);   // overlaps gu_pk (dead after gemm1)

    hipMemsetAsync(counts, 0, E_NUM * sizeof(int), stream);

    prep_kernel<<<7688, 256, 0, stream>>>(gu_q, gu_s, gu_pk, x, xb,
                                          router_logits, counts, lists, wlists);
    gemm1_packdn_kernel<<<5632, 256, 0, stream>>>(xb, gu_pk, counts, lists, act,
                                                  dn_q, dn_s, dn_pk);
    gemm2_kernel<<<16 * 16 * E_NUM, 256, 0, stream>>>(act, dn_pk, counts, lists, wlists, tmp);
    finalize_kernel<<<4096, 256, 0, stream>>>(tmp, out);
}

// Round 7
// 492.154 us; speedup vs baseline: 1.4090x; 1.0379x over previous
//
#include <hip/hip_runtime.h>
#include <hip/hip_bf16.h>

#define T_TOKENS 2048
#define H_DIM    2048
#define I_DIM    1408
#define E_NUM    8

typedef __bf16 bf16;
typedef __attribute__((ext_vector_type(8))) __bf16  bf16x8;
typedef __attribute__((ext_vector_type(4))) float   floatx4;

// ---------------- ws layout (bytes) ----------------
// gu_pk: [E][22 n-tiles][32 k-tiles][128 r][8 g] bf16x8, XOR-swizzled granules = 92.3 MB
// dn_pk: [E][16 n-tiles][22 k-tiles][128 r][8 g] bf16x8, swizzled              = 46.1 MB
// tmp overlaps gu_pk (gu_pk dead after gemm1; tmp written by gemm2).
static const size_t OFF_COUNTS = 0;
static const size_t OFF_LISTS  = 256;
static const size_t OFF_WLISTS = OFF_LISTS + (size_t)T_TOKENS * E_NUM * 4;       // 65792
static const size_t OFF_XB     = 131328;                                          // 8 MB
static const size_t OFF_ACT    = OFF_XB + (size_t)T_TOKENS * H_DIM * 2;           // 11.5 MB
static const size_t OFF_GUPK   = OFF_ACT + (size_t)2 * T_TOKENS * I_DIM * 2;
static const size_t OFF_DNPK   = OFF_GUPK + (size_t)E_NUM * 22 * 32 * 16384;
static const size_t OFF_TMP    = OFF_GUPK;   // 33.5 MB, overlapped

// async global->LDS, 16 B per lane; LDS dest is wave-uniform base + lane*16.
__device__ __forceinline__ void gload_lds16(const bf16* g, bf16* l)
{
    __builtin_amdgcn_global_load_lds((const __attribute__((address_space(1))) void*)g,
                                     (__attribute__((address_space(3))) void*)l,
                                     16, 0, 0);
}

// ================= K1: prep = pack_gu (5632) + xconv (2048) + router (8) =================
__global__ __launch_bounds__(256) void prep_kernel(
    const int*   __restrict__ gu_q,
    const float* __restrict__ gu_s,
    bf16*        __restrict__ gu_pk,
    const float* __restrict__ x,
    bf16*        __restrict__ xb,
    const float* __restrict__ logits,
    int*         __restrict__ counts,
    int*         __restrict__ lists,
    float*       __restrict__ wlists)
{
    const int bid = blockIdx.x;
    const int tid = threadIdx.x;

    if (bid < 5632) {
        // ---- pack_gu v2: one block per output tile, linear 16 KB writes ----
        const int kt  = bid & 31;
        const int en  = bid >> 5;
        const int nt  = en % 22;
        const int e   = en / 22;
        bf16x8* ob = reinterpret_cast<bf16x8*>(gu_pk) + (size_t)bid * 1024;
        #pragma unroll
        for (int j = 0; j < 4; ++j) {
            const int s     = tid + 256 * j;
            const int r     = s >> 3;
            const int gl    = (s & 7) ^ (r & 7);
            const int p2    = r >> 4;
            const int is_up = p2 & 1;
            const int icol  = nt * 64 + (p2 >> 1) * 16 + (r & 15);
            const size_t row_q = (size_t)e * 2816 + (is_up ? I_DIM : 0) + icol;
            const int4* qp = reinterpret_cast<const int4*>(gu_q + row_q * H_DIM + kt * 64 + gl * 8);
            int4 a = qp[0], c = qp[1];
            float sv = gu_s[row_q * 16 + (kt >> 1)];
            float m8 = -8.f * sv;
            bf16x8 bv;
            bv[0] = (bf16)fmaf((float)a.x, sv, m8);
            bv[1] = (bf16)fmaf((float)a.y, sv, m8);
            bv[2] = (bf16)fmaf((float)a.z, sv, m8);
            bv[3] = (bf16)fmaf((float)a.w, sv, m8);
            bv[4] = (bf16)fmaf((float)c.x, sv, m8);
            bv[5] = (bf16)fmaf((float)c.y, sv, m8);
            bv[6] = (bf16)fmaf((float)c.z, sv, m8);
            bv[7] = (bf16)fmaf((float)c.w, sv, m8);
            ob[s] = bv;
        }
    } else if (bid < 5632 + 2048) {
        // ---- xconv: f32 -> bf16, 8 elems/thread ----
        const int i = (bid - 5632) * 256 + tid;
        const float4* x4 = reinterpret_cast<const float4*>(x) + (size_t)i * 2;
        float4 v0 = x4[0], v1 = x4[1];
        bf16x8 bv;
        bv[0] = (bf16)v0.x; bv[1] = (bf16)v0.y; bv[2] = (bf16)v0.z; bv[3] = (bf16)v0.w;
        bv[4] = (bf16)v1.x; bv[5] = (bf16)v1.y; bv[6] = (bf16)v1.z; bv[7] = (bf16)v1.w;
        *reinterpret_cast<bf16x8*>(xb + (size_t)i * 8) = bv;
    } else {
        // ---- router ----
        const int t = (bid - 7680) * 256 + tid;
        const float* l = logits + (size_t)t * E_NUM;
        float v0 = -1e30f, v1 = -1e30f;
        int i0 = 0, i1 = 0;
        #pragma unroll
        for (int e = 0; e < E_NUM; ++e) {
            float v = l[e];
            if (v > v0) { v1 = v0; i1 = i0; v0 = v; i0 = e; }
            else if (v > v1) { v1 = v; i1 = e; }
        }
        float w0 = 1.f / (1.f + __expf(v1 - v0));
        float w1 = 1.f - w0;
        int p0 = atomicAdd(&counts[i0], 1);
        lists[i0 * T_TOKENS + p0] = t * 2 + 0;
        wlists[i0 * T_TOKENS + p0] = w0;
        int p1 = atomicAdd(&counts[i1], 1);
        lists[i1 * T_TOKENS + p1] = t * 2 + 1;
        wlists[i1 * T_TOKENS + p1] = w1;
    }
}

// ================= K2: gemm1 M=64 (blocks 0..5631) + pack_dn (5632..8447) =================
// M-tile halved to 64 vs round-5: live gemm1 blocks double (~1400, ~5.5/CU) for
// more inter-block TLP (the proven lever; intra-block pipelining failed R2/R3).
// LDS/block 24.6 KB -> 6 blocks/CU. Same staging/swizzle/2-barrier structure.
__global__ __launch_bounds__(256) void gemm1_packdn_kernel(
    const bf16*  __restrict__ xb,
    const bf16*  __restrict__ wpk,
    const int*   __restrict__ counts,
    const int*   __restrict__ lists,
    bf16*        __restrict__ act,
    const int*   __restrict__ dn_q,
    const float* __restrict__ dn_s,
    bf16*        __restrict__ dn_pk)
{
    const int tid = threadIdx.x;

    if (blockIdx.x >= 5632) {
        // ---- pack_dn v2: linear writes ----
        const int pbid = blockIdx.x - 5632;
        const int kt  = pbid % 22;
        const int en  = pbid / 22;
        const int nt  = en & 15;
        const int e   = en >> 4;
        bf16x8* ob = reinterpret_cast<bf16x8*>(dn_pk) + (size_t)pbid * 1024;
        #pragma unroll
        for (int j = 0; j < 4; ++j) {
            const int s  = tid + 256 * j;
            const int r  = s >> 3;
            const int gl = (s & 7) ^ (r & 7);
            const size_t row_q = (size_t)e * 2048 + nt * 128 + r;
            const int4* qp = reinterpret_cast<const int4*>(dn_q + row_q * I_DIM + kt * 64 + gl * 8);
            int4 a = qp[0], c = qp[1];
            float sv = dn_s[row_q * 11 + (kt >> 1)];
            float m8 = -8.f * sv;
            bf16x8 bv;
            bv[0] = (bf16)fmaf((float)a.x, sv, m8);
            bv[1] = (bf16)fmaf((float)a.y, sv, m8);
            bv[2] = (bf16)fmaf((float)a.z, sv, m8);
            bv[3] = (bf16)fmaf((float)a.w, sv, m8);
            bv[4] = (bf16)fmaf((float)c.x, sv, m8);
            bv[5] = (bf16)fmaf((float)c.y, sv, m8);
            bv[6] = (bf16)fmaf((float)c.z, sv, m8);
            bv[7] = (bf16)fmaf((float)c.w, sv, m8);
            ob[s] = bv;
        }
        return;
    }

    // ---- gemm1, M=64: xb @ W_gate_up^T, fused SwiGLU ----
    // XCD-pinned: lid = (bid&7)*704 + bid>>3 -> expert = XCD; m-tile fastest.
    const int lid = (blockIdx.x & 7) * 704 + (blockIdx.x >> 3);
    const int e   = lid / 704;
    const int r_  = lid - e * 704;
    const int nt  = r_ >> 5;         // 0..21, 64 I-cols per tile
    const int m0  = (r_ & 31) << 6;  // 0..1984
    const int cnt = counts[e];
    if (m0 >= cnt) return;

    __shared__ __align__(16) bf16 Al[4096];    // 64 x 64
    __shared__ __align__(16) bf16 Bl[8192];    // 128 x 64
    __shared__ int meta[64];

    if (tid < 64) {
        int m = m0 + tid;
        meta[tid] = lists[e * T_TOKENS + (m < cnt ? m : 0)];
    }
    __syncthreads();

    const int lane = tid & 63;
    const int wv = tid >> 6;
    const int wm = wv >> 1, wn = wv & 1;

    // A staging: 2 granule-slots/thread (slot g = tid + 256j, row = g>>3)
    size_t agbl[2];
    #pragma unroll
    for (int j = 0; j < 2; ++j) {
        int g = tid + 256 * j;
        int arow = g >> 3, cg = g & 7;
        agbl[j] = (size_t)(meta[arow] >> 1) * H_DIM + ((cg ^ (arow & 7)) * 8);
    }
    const bf16* bt = wpk + ((size_t)e * 22 + nt) * (32 * 8192) + tid * 8;

    // fragment read offsets: A rows wm*32 + mt*16, B rows wn*64 + t4*16
    int afr[2][2], bfr[2][4];
    #pragma unroll
    for (int ks = 0; ks < 2; ++ks) {
        int gidx = ks * 4 + (lane >> 4);
        #pragma unroll
        for (int t4 = 0; t4 < 2; ++t4) {
            int ra = wm * 32 + t4 * 16 + (lane & 15);
            afr[ks][t4] = ra * 64 + ((gidx ^ (ra & 7)) * 8);
        }
        #pragma unroll
        for (int t4 = 0; t4 < 4; ++t4) {
            int rb = wn * 64 + t4 * 16 + (lane & 15);
            bfr[ks][t4] = rb * 64 + ((gidx ^ (rb & 7)) * 8);
        }
    }

    floatx4 acc[2][4];
    #pragma unroll
    for (int i = 0; i < 2; ++i)
        #pragma unroll
        for (int j = 0; j < 4; ++j)
            acc[i][j] = (floatx4){0.f, 0.f, 0.f, 0.f};

    for (int k0 = 0; k0 < H_DIM; k0 += 64) {
        #pragma unroll
        for (int j = 0; j < 2; ++j)
            gload_lds16(xb + agbl[j] + k0, &Al[(tid + 256 * j) * 8]);
        const bf16* bsrc = bt + (size_t)(k0 >> 6) * 8192;
        #pragma unroll
        for (int j = 0; j < 4; ++j)
            gload_lds16(bsrc + j * 2048, &Bl[tid * 8 + j * 2048]);
        __syncthreads();
        #pragma unroll
        for (int ks = 0; ks < 2; ++ks) {
            bf16x8 af[2], bff[4];
            #pragma unroll
            for (int mt = 0; mt < 2; ++mt)
                af[mt] = *reinterpret_cast<const bf16x8*>(&Al[afr[ks][mt]]);
            #pragma unroll
            for (int ntf = 0; ntf < 4; ++ntf)
                bff[ntf] = *reinterpret_cast<const bf16x8*>(&Bl[bfr[ks][ntf]]);
            #pragma unroll
            for (int mt = 0; mt < 2; ++mt)
                #pragma unroll
                for (int ntf = 0; ntf < 4; ++ntf)
                    acc[mt][ntf] = __builtin_amdgcn_mfma_f32_16x16x32_bf16(af[mt], bff[ntf], acc[mt][ntf], 0, 0, 0);
        }
        __syncthreads();
    }

    // epilogue: SwiGLU (gate = even col-frag, up = odd), scatter to act
    const int rbase = (lane >> 4) * 4;
    const int cn = lane & 15;
    #pragma unroll
    for (int mt = 0; mt < 2; ++mt) {
        #pragma unroll
        for (int j = 0; j < 2; ++j) {
            floatx4 g = acc[mt][2 * j];
            floatx4 u = acc[mt][2 * j + 1];
            int col = nt * 64 + (wn * 2 + j) * 16 + cn;
            #pragma unroll
            for (int r = 0; r < 4; ++r) {
                int lrow = wm * 32 + mt * 16 + rbase + r;
                if (m0 + lrow < cnt) {
                    float gate = g[r], up = u[r];
                    float a = gate / (1.f + __expf(-gate)) * up;
                    act[(size_t)meta[lrow] * I_DIM + col] = (bf16)a;
                }
            }
        }
    }
}

// ---------------- GEMM2 M=64: act @ W_down^T, weighted write to tmp ----------------
__global__ __launch_bounds__(256) void gemm2_kernel(
    const bf16*  __restrict__ act,
    const bf16*  __restrict__ wpk,
    const int*   __restrict__ counts,
    const int*   __restrict__ lists,
    const float* __restrict__ wlists,
    float*       __restrict__ tmp)
{
    // 4096 = 8 * 512, one expert per XCD, m-tile fastest
    const int lid = (blockIdx.x & 7) * 512 + (blockIdx.x >> 3);
    const int e   = lid >> 9;
    const int r_  = lid & 511;
    const int nt  = r_ >> 5;        // 0..15, 128 H-cols per tile
    const int m0  = (r_ & 31) << 6;
    const int cnt = counts[e];
    if (m0 >= cnt) return;

    __shared__ __align__(16) bf16 Al[4096];
    __shared__ __align__(16) bf16 Bl[8192];
    __shared__ int   meta[64];
    __shared__ float wmeta[64];

    const int tid = threadIdx.x;
    if (tid < 64) {
        int m = m0 + tid;
        int mm = (m < cnt) ? m : 0;
        meta[tid]  = lists[e * T_TOKENS + mm];
        wmeta[tid] = wlists[e * T_TOKENS + mm];
    }
    __syncthreads();

    const int lane = tid & 63;
    const int wv = tid >> 6;
    const int wm = wv >> 1, wn = wv & 1;

    size_t agbl[2];
    #pragma unroll
    for (int j = 0; j < 2; ++j) {
        int g = tid + 256 * j;
        int arow = g >> 3, cg = g & 7;
        agbl[j] = (size_t)meta[arow] * I_DIM + ((cg ^ (arow & 7)) * 8);
    }
    const bf16* bt = wpk + ((size_t)e * 16 + nt) * (22 * 8192) + tid * 8;

    int afr[2][2], bfr[2][4];
    #pragma unroll
    for (int ks = 0; ks < 2; ++ks) {
        int gidx = ks * 4 + (lane >> 4);
        #pragma unroll
        for (int t4 = 0; t4 < 2; ++t4) {
            int ra = wm * 32 + t4 * 16 + (lane & 15);
            afr[ks][t4] = ra * 64 + ((gidx ^ (ra & 7)) * 8);
        }
        #pragma unroll
        for (int t4 = 0; t4 < 4; ++t4) {
            int rb = wn * 64 + t4 * 16 + (lane & 15);
            bfr[ks][t4] = rb * 64 + ((gidx ^ (rb & 7)) * 8);
        }
    }

    floatx4 acc[2][4];
    #pragma unroll
    for (int i = 0; i < 2; ++i)
        #pragma unroll
        for (int j = 0; j < 4; ++j)
            acc[i][j] = (floatx4){0.f, 0.f, 0.f, 0.f};

    for (int kt = 0; kt < 22; ++kt) {
        #pragma unroll
        for (int j = 0; j < 2; ++j)
            gload_lds16(act + agbl[j] + kt * 64, &Al[(tid + 256 * j) * 8]);
        const bf16* bsrc = bt + (size_t)kt * 8192;
        #pragma unroll
        for (int j = 0; j < 4; ++j)
            gload_lds16(bsrc + j * 2048, &Bl[tid * 8 + j * 2048]);
        __syncthreads();
        #pragma unroll
        for (int ks = 0; ks < 2; ++ks) {
            bf16x8 af[2], bff[4];
            #pragma unroll
            for (int mt = 0; mt < 2; ++mt)
                af[mt] = *reinterpret_cast<const bf16x8*>(&Al[afr[ks][mt]]);
            #pragma unroll
            for (int ntf = 0; ntf < 4; ++ntf)
                bff[ntf] = *reinterpret_cast<const bf16x8*>(&Bl[bfr[ks][ntf]]);
            #pragma unroll
            for (int mt = 0; mt < 2; ++mt)
                #pragma unroll
                for (int ntf = 0; ntf < 4; ++ntf)
                    acc[mt][ntf] = __builtin_amdgcn_mfma_f32_16x16x32_bf16(af[mt], bff[ntf], acc[mt][ntf], 0, 0, 0);
        }
        __syncthreads();
    }

    const int rbase = (lane >> 4) * 4;
    const int cn = lane & 15;
    #pragma unroll
    for (int mt = 0; mt < 2; ++mt) {
        #pragma unroll
        for (int ntf = 0; ntf < 4; ++ntf) {
            floatx4 v = acc[mt][ntf];
            int col = nt * 128 + wn * 64 + ntf * 16 + cn;
            #pragma unroll
            for (int r = 0; r < 4; ++r) {
                int lrow = wm * 32 + mt * 16 + rbase + r;
                if (m0 + lrow < cnt) {
                    tmp[(size_t)meta[lrow] * H_DIM + col] = wmeta[lrow] * v[r];
                }
            }
        }
    }
}

// ---------------- finalize: out[t] = tmp[2t] + tmp[2t+1] ----------------
__global__ void finalize_kernel(const float* __restrict__ tmp, float* __restrict__ out)
{
    int i4 = blockIdx.x * blockDim.x + threadIdx.x;
    int t  = i4 >> 9;
    int h  = (i4 & 511) * 4;
    float4 a = *reinterpret_cast<const float4*>(tmp + ((size_t)2 * t) * H_DIM + h);
    float4 b = *reinterpret_cast<const float4*>(tmp + ((size_t)(2 * t + 1)) * H_DIM + h);
    float4 o;
    o.x = a.x + b.x; o.y = a.y + b.y; o.z = a.z + b.z; o.w = a.w + b.w;
    *reinterpret_cast<float4*>(out + (size_t)t * H_DIM + h) = o;
}

extern "C" void kernel_launch(void* const* d_in, const int* in_sizes, int n_in,
                              void* d_out, int out_size, void* d_ws, size_t ws_size,
                              hipStream_t stream)
{
    const float* router_logits = (const float*)d_in[0];
    const float* x             = (const float*)d_in[1];
    const int*   gu_q          = (const int*)d_in[2];
    const float* gu_s          = (const float*)d_in[3];
    const int*   dn_q          = (const int*)d_in[4];
    const float* dn_s          = (const float*)d_in[5];
    float* out = (float*)d_out;

    char* ws = (char*)d_ws;
    int*   counts = (int*)(ws + OFF_COUNTS);
    int*   lists  = (int*)(ws + OFF_LISTS);
    float* wlists = (float*)(ws + OFF_WLISTS);
    bf16*  xb     = (bf16*)(ws + OFF_XB);
    bf16*  act    = (bf16*)(ws + OFF_ACT);
    bf16*  gu_pk  = (bf16*)(ws + OFF_GUPK);
    bf16*  dn_pk  = (bf16*)(ws + OFF_DNPK);
    float* tmp    = (float*)(ws + OFF_TMP);   // overlaps gu_pk (dead after gemm1)

    hipMemsetAsync(counts, 0, E_NUM * sizeof(int), stream);

    prep_kernel<<<7688, 256, 0, stream>>>(gu_q, gu_s, gu_pk, x, xb,
                                          router_logits, counts, lists, wlists);
    gemm1_packdn_kernel<<<8448, 256, 0, stream>>>(xb, gu_pk, counts, lists, act,
                                                  dn_q, dn_s, dn_pk);
    gemm2_kernel<<<4096, 256, 0, stream>>>(act, dn_pk, counts, lists, wlists, tmp);
    finalize_kernel<<<4096, 256, 0, stream>>>(tmp, out);
}